// Round 17
// baseline (691.901 us; speedup 1.0000x reference)
//
#include <hip/hip_runtime.h>
#include <hip/hip_bf16.h>
#include <math.h>

#define B_ 4
#define N_ 4096
#define K_ 20
#define NK_ (N_*K_)   // 81920
#define G_ 16
#define EPS_ 1e-5f
#define NBLK_ (NK_/256)   // 320 column-blocks per batch

typedef __hip_bfloat16 bf16;
typedef short bf16x8v __attribute__((ext_vector_type(8)));
typedef unsigned short u16x8v __attribute__((ext_vector_type(8)));
typedef unsigned short u16x4v __attribute__((ext_vector_type(4)));
typedef float f32x4v __attribute__((ext_vector_type(4)));

__device__ inline float b2f(bf16 v) { return __bfloat162float(v); }
__device__ inline bf16  f2b(float v){ return __float2bfloat16(v); }
__device__ inline float us2f(unsigned short u){ unsigned int i = ((unsigned)u) << 16; float f; __builtin_memcpy(&f, &i, 4); return f; }
__device__ inline unsigned short f2us(float f){ bf16 h = __float2bfloat16(f); unsigned short u; __builtin_memcpy(&u, &h, 2); return u; }

// ---------------- kNN: one WAVE per (b,i); max3-tree + eq-rescan + scalar retire ----------------
// pd arithmetic bit-exact np (no FMA, sequential adds) — LOAD-BEARING, do not change.
// Rank 0 is always self (pd[i,i]=+0 strict max); ranks 1..19 extracted iteratively.
__global__ __launch_bounds__(256) void knn_kernel(const float* __restrict__ pts, int* __restrict__ idx)
{
    int wid  = (blockIdx.x << 2) | (threadIdx.x >> 6);   // global wave id = b*N + i
    int lane = threadIdx.x & 63;
    int b = wid >> 12, i = wid & (N_ - 1);
    const float* pb = pts + (size_t)b * 6 * N_;
    float xi = pb[i], yi = pb[N_ + i], zi = pb[2 * N_ + i];
    float xxi = __fadd_rn(__fadd_rn(__fmul_rn(xi, xi), __fmul_rn(yi, yi)), __fmul_rn(zi, zi));
    float nxxi = -xxi;

    float pd[64];                    // candidate j = c*64 + lane (statically indexed only)
    #pragma unroll
    for (int c = 0; c < 64; ++c) {
        int j = c * 64 + lane;
        float xj = pb[j], yj = pb[N_ + j], zj = pb[2 * N_ + j];
        float xxj = __fadd_rn(__fadd_rn(__fmul_rn(xj, xj), __fmul_rn(yj, yj)), __fmul_rn(zj, zj));
        float px = __fmul_rn(xi, xj);
        float py = __fmul_rn(yi, yj);
        float pz = __fmul_rn(zi, zj);
        float dot = __fadd_rn(__fadd_rn(px, py), pz);   // NO FMA — matches np
        float inner = __fmul_rn(-2.0f, dot);
        pd[c] = __fsub_rn(__fsub_rn(nxxi, inner), xxj);
    }

    // rank 0 = self: emit and retire (pd[i,i] = +0 exactly; all others < 0)
    {
        int slot = __builtin_amdgcn_readfirstlane(i >> 6);
        int ln   = __builtin_amdgcn_readfirstlane(i & 63);
        bool me = (lane == ln);
        #pragma unroll
        for (int c = 0; c < 64; ++c)
            if (c == slot) pd[c] = me ? -INFINITY : pd[c];
        if (lane == 0) idx[(size_t)b * NK_ + i] = i;
    }

    for (int it = 1; it < K_; ++it) {
        // lane-local max via max3 tree (~32 ops)
        float m0[22];
        #pragma unroll
        for (int g = 0; g < 21; ++g)
            m0[g] = fmaxf(fmaxf(pd[3 * g], pd[3 * g + 1]), pd[3 * g + 2]);
        m0[21] = pd[63];
        float m1[8];
        #pragma unroll
        for (int g = 0; g < 7; ++g)
            m1[g] = fmaxf(fmaxf(m0[3 * g], m0[3 * g + 1]), m0[3 * g + 2]);
        m1[7] = m0[21];
        float m20 = fmaxf(fmaxf(m1[0], m1[1]), m1[2]);
        float m21 = fmaxf(fmaxf(m1[3], m1[4]), m1[5]);
        float vb  = fmaxf(fmaxf(m20, m21), fmaxf(m1[6], m1[7]));

        // largest matching slot in this lane (ascending overwrite -> largest c)
        int cm = 0;
        #pragma unroll
        for (int c = 0; c < 64; ++c)
            if (pd[c] == vb) cm = c;
        int j = cm * 64 + lane;

        // butterfly argmax: value first, larger j on exact value ties (matches np path)
        float bv = vb; int bj = j;
        #pragma unroll
        for (int off = 1; off < 64; off <<= 1) {
            float ov = __shfl_xor(bv, off);
            int   oj = __shfl_xor(bj, off);
            if (ov > bv || (ov == bv && oj > bj)) { bv = ov; bj = oj; }
        }
        if (lane == 0) idx[(size_t)b * NK_ + it * N_ + i] = bj;

        // retire exactly the winner: slot is wave-uniform -> scalar branch
        int slot = __builtin_amdgcn_readfirstlane(bj >> 6);
        int ln   = __builtin_amdgcn_readfirstlane(bj & 63);
        bool me = (lane == ln);
        #pragma unroll
        for (int c = 0; c < 64; ++c)
            if (c == slot) pd[c] = me ? -INFINITY : pd[c];
    }
}

// ---------------- angle: "x<0" quadrant predicate — LOAD-BEARING (round 10) ----------------
__device__ inline float angle3(float ax, float ay, float az, float bx, float by, float bz)
{
    float cx = __fsub_rn(__fmul_rn(ay, bz), __fmul_rn(az, by));
    float cy = __fsub_rn(__fmul_rn(az, bx), __fmul_rn(ax, bz));
    float cz = __fsub_rn(__fmul_rn(ax, by), __fmul_rn(ay, bx));
    float cn = sqrtf(__fadd_rn(__fadd_rn(__fmul_rn(cx, cx), __fmul_rn(cy, cy)), __fmul_rn(cz, cz)));
    float d  = __fadd_rn(__fadd_rn(__fmul_rn(ax, bx), __fmul_rn(ay, by)), __fmul_rn(az, bz));
    if (cn == 0.0f)
        return (d < 0.0f) ? 3.14159274101257324e+00f : 0.0f;   // -0 -> 0
    return atan2f(cn, d);
}

__global__ __launch_bounds__(256) void feature_kernel(const float* __restrict__ pts,
                                                      const int* __restrict__ idx,
                                                      float* __restrict__ x0)
{
    int t = blockIdx.x * 256 + threadIdx.x;           // [0, B*NK)
    int col = t % NK_;
    int b = t / NK_;
    int n = col & (N_ - 1);
    int j = idx[t];
    const float* pb = pts + (size_t)b * 6 * N_;
    float cx = pb[n],            cy = pb[N_ + n],     cz = pb[2 * N_ + n];
    float gx = pb[j],            gy = pb[N_ + j],     gz = pb[2 * N_ + j];
    float rx = pb[3 * N_ + n],   ry = pb[4 * N_ + n], rz = pb[5 * N_ + n];
    float ix = pb[3 * N_ + j],   iy = pb[4 * N_ + j], iz = pb[5 * N_ + j];
    float lx = __fsub_rn(gx, cx), ly = __fsub_rn(gy, cy), lz = __fsub_rn(gz, cz);

    float f9  = angle3(rx, ry, rz, lx, ly, lz);
    float f10 = angle3(ix, iy, iz, lx, ly, lz);
    float f11 = angle3(rx, ry, rz, ix, iy, iz);
    float f12 = sqrtf(__fadd_rn(__fadd_rn(__fmul_rn(lx, lx), __fmul_rn(ly, ly)), __fmul_rn(lz, lz)));

    float* xp = x0 + (size_t)b * 13 * NK_ + col;
    xp[0  * (size_t)NK_] = gx;
    xp[1  * (size_t)NK_] = gy;
    xp[2  * (size_t)NK_] = gz;
    xp[3  * (size_t)NK_] = cx;
    xp[4  * (size_t)NK_] = cy;
    xp[5  * (size_t)NK_] = cz;
    xp[6  * (size_t)NK_] = lx;
    xp[7  * (size_t)NK_] = ly;
    xp[8  * (size_t)NK_] = lz;
    xp[9  * (size_t)NK_] = f9;
    xp[10 * (size_t)NK_] = f10;
    xp[11 * (size_t)NK_] = f11;
    xp[12 * (size_t)NK_] = f12;
}

// ---------------- deterministic block reduction: 16 sums + 16 sumsqs -> 32 partials ----------------
__device__ inline void block_reduce_write(const float gsum[16], const float gsq[16], float* __restrict__ dst)
{
    __shared__ float red[4][32];
    int t = threadIdx.x, lane = t & 63, w = t >> 6;
    #pragma unroll
    for (int r = 0; r < 16; ++r) {
        float v = gsum[r];
        #pragma unroll
        for (int off = 32; off > 0; off >>= 1) v += __shfl_down(v, off);
        if (lane == 0) red[w][r] = v;
        float q = gsq[r];
        #pragma unroll
        for (int off = 32; off > 0; off >>= 1) q += __shfl_down(q, off);
        if (lane == 0) red[w][16 + r] = q;
    }
    __syncthreads();
    if (t < 32) dst[t] = red[0][t] + red[1][t] + red[2][t] + red[3][t];
}

// ---------------- stage1: conv1 -> GN1 partial stats (y1 never stored) ----------------
__global__ __launch_bounds__(256) void stage1_kernel(const float* __restrict__ x0,
    const float* __restrict__ W1, float* __restrict__ p1)
{
    int b = blockIdx.y;
    int col = blockIdx.x * 256 + threadIdx.x;
    const float* xb = x0 + (size_t)b * 13 * NK_ + col;
    float xr[13];
    #pragma unroll
    for (int c = 0; c < 13; ++c) xr[c] = xb[(size_t)c * NK_];
    float gsum[16], gsq[16];
    #pragma unroll
    for (int g = 0; g < 16; ++g) {
        float sg = 0.f, qg = 0.f;
        for (int oi = 0; oi < 4; ++oi) {
            int o = g * 4 + oi;
            float acc = 0.f;
            #pragma unroll
            for (int c = 0; c < 13; ++c) acc = fmaf(W1[o * 13 + c], xr[c], acc);
            sg += acc; qg += acc * acc;
        }
        gsum[g] = sg; gsq[g] = qg;
    }
    block_reduce_write(gsum, gsq, p1 + ((size_t)b * NBLK_ + blockIdx.x) * 32);
}

// ---------------- stage2: conv1+GN1+relu+conv2 -> y2g [b][cg=8][col][8c] + GN2 stats ----------------
__global__ __launch_bounds__(256) void stage2_kernel(const float* __restrict__ x0,
    const float* __restrict__ W1, const float* __restrict__ a1, const float* __restrict__ s1,
    const float* __restrict__ W2, unsigned short* __restrict__ y2g, float* __restrict__ p2)
{
    __shared__ float aL[64], sL[64];
    int b = blockIdx.y;
    int col = blockIdx.x * 256 + threadIdx.x;
    if (threadIdx.x < 64) {
        aL[threadIdx.x] = a1[b * 64 + threadIdx.x];
        sL[threadIdx.x] = s1[b * 64 + threadIdx.x];
    }
    __syncthreads();
    const float* xb = x0 + (size_t)b * 13 * NK_ + col;
    float xr[13];
    #pragma unroll
    for (int c = 0; c < 13; ++c) xr[c] = xb[(size_t)c * NK_];
    float y1r[64];
    #pragma unroll
    for (int o = 0; o < 64; ++o) {
        float acc = 0.f;
        #pragma unroll
        for (int c = 0; c < 13; ++c) acc = fmaf(W1[o * 13 + c], xr[c], acc);
        y1r[o] = fmaxf(fmaf(acc, aL[o], sL[o]), 0.f);
    }
    float gsum[16], gsq[16];
    #pragma unroll
    for (int r = 0; r < 16; ++r) { gsum[r] = 0.f; gsq[r] = 0.f; }
    #pragma unroll
    for (int og = 0; og < 8; ++og) {
        u16x8v row;
        #pragma unroll
        for (int oi = 0; oi < 8; ++oi) {
            int o = og * 8 + oi;
            float acc = 0.f;
            #pragma unroll
            for (int c = 0; c < 64; ++c) acc = fmaf(W2[o * 64 + c], y1r[c], acc);
            row[oi] = f2us(acc);
            gsum[og * 2 + (oi >> 2)] += acc;           // GN group o>>2, compile-time index
            gsq[og * 2 + (oi >> 2)] += acc * acc;      // stats on pre-rounding fp32
        }
        *reinterpret_cast<u16x8v*>(y2g + (((size_t)b * 8 + og) * NK_ + col) * 8) = row;
    }
    block_reduce_write(gsum, gsq, p2 + ((size_t)b * NBLK_ + blockIdx.x) * 32);
}

// ---------------- fold GN into per-(b,c) scale/shift from block partials ----------------
template<int COUT>
__global__ __launch_bounds__(256) void finalize_kernel(const float* __restrict__ part,
    const float* __restrict__ gamma, const float* __restrict__ beta,
    float* __restrict__ ga, float* __restrict__ sh)
{
    int t = blockIdx.x * 256 + threadIdx.x;
    if (t >= B_ * COUT) return;
    int b = t / COUT, c = t % COUT;
    int g = c / (COUT / G_);
    float sum = 0.f, sq = 0.f;
    for (int blk = 0; blk < NBLK_; ++blk) {
        sum += part[((size_t)b * NBLK_ + blk) * 32 + g];
        sq  += part[((size_t)b * NBLK_ + blk) * 32 + 16 + g];
    }
    float cnt = (float)(COUT / G_) * (float)NK_;
    float mean = sum / cnt;
    float var = fmaxf(sq / cnt - mean * mean, 0.f);
    float sc = gamma[c] * rsqrtf(var + EPS_);
    ga[t] = sc;
    sh[t] = beta[c] - mean * sc;
}

// ---------------- weight -> bf16 casts ----------------
__global__ __launch_bounds__(256) void wcast_kernel(const float* __restrict__ W, bf16* __restrict__ Wb, int n)
{
    int t = blockIdx.x * 256 + threadIdx.x;
    if (t < n) Wb[t] = f2b(W[t]);
}

// ---------------- prep2: in-place x2 = bf16(relu(a2*y2 + s2)) on y2g [b][cg=8][col][8c] ----------------
__global__ __launch_bounds__(256) void prep2_kernel(unsigned short* __restrict__ y2g,
    const float* __restrict__ a2, const float* __restrict__ s2)
{
    size_t t = (size_t)blockIdx.x * 256 + threadIdx.x;   // one (b,cg,col) 16B chunk
    int b  = (int)(t / ((size_t)8 * NK_));
    int cg = (int)((t / NK_) & 7);
    const float* ab = a2 + b * 64 + cg * 8;
    const float* sb = s2 + b * 64 + cg * 8;
    u16x8v v = *reinterpret_cast<const u16x8v*>(y2g + t * 8);
    #pragma unroll
    for (int j = 0; j < 8; ++j)
        v[j] = f2us(fmaxf(fmaf(us2f(v[j]), ab[j], sb[j]), 0.f));
    *reinterpret_cast<u16x8v*>(y2g + t * 8) = v;
}

// ---------------- stage3 via MFMA: y3 = W3 x x2 -> y3g grouped + GN3 partials ----------------
__global__ __launch_bounds__(256) void stage3_mfma_kernel(
    const short* __restrict__ x2g, const short* __restrict__ w3b,
    unsigned short* __restrict__ y3g, float* __restrict__ p3m)
{
    int ntile = blockIdx.x, b = blockIdx.z;
    int lane = threadIdx.x & 63, w = threadIdx.x >> 6;
    int colbase = ntile * 16 + (lane & 15);
    int cme = (lane >> 4) * 8;

    bf16x8v afr[8][2];
    #pragma unroll
    for (int ot = 0; ot < 8; ++ot)
        #pragma unroll
        for (int kb = 0; kb < 2; ++kb)
            afr[ot][kb] = *reinterpret_cast<const bf16x8v*>(
                w3b + (size_t)(ot * 16 + (lane & 15)) * 64 + kb * 32 + cme);

    float psum[8], psq[8];
    #pragma unroll
    for (int ot = 0; ot < 8; ++ot) { psum[ot] = 0.f; psq[ot] = 0.f; }

    for (int kk = 0; kk < 5; ++kk) {
        int k = kk * 4 + w;
        int colme = k * N_ + colbase;
        bf16x8v bfr[2];
        #pragma unroll
        for (int kb = 0; kb < 2; ++kb) {
            int cg = kb * 4 + (lane >> 4);
            bfr[kb] = *reinterpret_cast<const bf16x8v*>(
                x2g + (((size_t)b * 8 + cg) * NK_ + colme) * 8);
        }
        #pragma unroll
        for (int ot = 0; ot < 8; ++ot) {
            f32x4v acc = { 0.f, 0.f, 0.f, 0.f };
            acc = __builtin_amdgcn_mfma_f32_16x16x32_bf16(afr[ot][0], bfr[0], acc, 0, 0, 0);
            acc = __builtin_amdgcn_mfma_f32_16x16x32_bf16(afr[ot][1], bfr[1], acc, 0, 0, 0);
            u16x4v sv;
            #pragma unroll
            for (int j = 0; j < 4; ++j) {
                float v = acc[j];
                sv[j] = f2us(v);
                psum[ot] += v; psq[ot] += v * v;
            }
            int g = ot * 2 + (lane >> 5);
            *reinterpret_cast<u16x4v*>(
                y3g + (((size_t)b * 16 + g) * NK_ + colme) * 8 + ((lane >> 4) & 1) * 4) = sv;
        }
    }
    float* dst = p3m + ((size_t)(b * 256 + ntile) * 4 + w) * 32;
    #pragma unroll
    for (int ot = 0; ot < 8; ++ot) {
        float s = psum[ot], q = psq[ot];
        #pragma unroll
        for (int off = 16; off > 0; off >>= 1) {
            s += __shfl_down(s, off, 32);
            q += __shfl_down(q, off, 32);
        }
        if ((lane & 31) == 0) {
            int half = lane >> 5;
            dst[ot * 4 + half * 2 + 0] = s;
            dst[ot * 4 + half * 2 + 1] = q;
        }
    }
}

// ---------------- GN3 finalize from stage3_mfma partials ----------------
__global__ __launch_bounds__(256) void finalize3_kernel(const float* __restrict__ p3m,
    const float* __restrict__ gamma, const float* __restrict__ beta,
    float* __restrict__ ga, float* __restrict__ sh)
{
    int t = blockIdx.x * 256 + threadIdx.x;   // B*128
    if (t >= B_ * 128) return;
    int b = t >> 7, c = t & 127;
    int g = c >> 3;
    int e = (g >> 1) * 4 + (g & 1) * 2;
    float sum = 0.f, sq = 0.f;
    for (int s = 0; s < 1024; ++s) {          // ntile*4 + w
        const float* d = p3m + ((size_t)(b * 1024 + s)) * 32;
        sum += d[e]; sq += d[e + 1];
    }
    float cnt = 8.f * (float)NK_;
    float mean = sum / cnt;
    float var = fmaxf(sq / cnt - mean * mean, 0.f);
    float sc = gamma[c] * rsqrtf(var + EPS_);
    ga[t] = sc;
    sh[t] = beta[c] - mean * sc;
}

// ---------------- prep4: in-place x3 = bf16(relu(a3*y3 + s3)) on y3g [b][cg][col][8c] ----------------
__global__ __launch_bounds__(256) void prep4_kernel(unsigned short* __restrict__ y3g,
    const float* __restrict__ a3, const float* __restrict__ s3)
{
    size_t t = (size_t)blockIdx.x * 256 + threadIdx.x;   // one (b,cg,col) 16B chunk
    int b  = (int)(t / ((size_t)16 * NK_));
    int cg = (int)((t / NK_) & 15);
    const float* ab = a3 + b * 128 + cg * 8;
    const float* sb = s3 + b * 128 + cg * 8;
    u16x8v v = *reinterpret_cast<const u16x8v*>(y3g + t * 8);
    #pragma unroll
    for (int j = 0; j < 8; ++j)
        v[j] = f2us(fmaxf(fmaf(us2f(v[j]), ab[j], sb[j]), 0.f));
    *reinterpret_cast<u16x8v*>(y3g + t * 8) = v;
}

// ---------------- conv4 via MFMA: block = 16n tile, 4 waves x 4 o-passes = all 256 o ----------------
__global__ __launch_bounds__(256) void conv4_mfma_kernel(
    const short* __restrict__ x3g, const short* __restrict__ w4b,
    float* __restrict__ m4, float* __restrict__ part)
{
    int ntile = blockIdx.x, b = blockIdx.z;
    int lane = threadIdx.x & 63, w = threadIdx.x >> 6;
    int colme = ntile * 16 + (lane & 15);
    int cme = (lane >> 4) * 8;

    bf16x8v afr[4][4];
    #pragma unroll
    for (int p = 0; p < 4; ++p) {
        #pragma unroll
        for (int cb = 0; cb < 4; ++cb) {
            size_t aoff = (size_t)(p * 64 + w * 16 + (lane & 15)) * 128 + cb * 32 + cme;
            afr[p][cb] = *reinterpret_cast<const bf16x8v*>(w4b + aoff);
        }
    }

    float am[4][4];
    #pragma unroll
    for (int p = 0; p < 4; ++p)
        #pragma unroll
        for (int j = 0; j < 4; ++j) am[p][j] = -INFINITY;
    float ps[4] = {0.f, 0.f, 0.f, 0.f}, pq[4] = {0.f, 0.f, 0.f, 0.f};

    for (int k = 0; k < K_; ++k) {
        bf16x8v bfr[4];
        #pragma unroll
        for (int cb = 0; cb < 4; ++cb) {
            int cg = cb * 4 + (lane >> 4);
            bfr[cb] = *reinterpret_cast<const bf16x8v*>(
                x3g + (((size_t)b * 16 + cg) * NK_ + (size_t)k * N_ + colme) * 8);
        }
        #pragma unroll
        for (int p = 0; p < 4; ++p) {
            f32x4v acc = { 0.f, 0.f, 0.f, 0.f };
            #pragma unroll
            for (int cb = 0; cb < 4; ++cb)
                acc = __builtin_amdgcn_mfma_f32_16x16x32_bf16(afr[p][cb], bfr[cb], acc, 0, 0, 0);
            #pragma unroll
            for (int j = 0; j < 4; ++j) {
                float v = acc[j];
                am[p][j] = fmaxf(am[p][j], v);
                ps[p] += v; pq[p] += v * v;
            }
        }
    }
    #pragma unroll
    for (int p = 0; p < 4; ++p) {
        #pragma unroll
        for (int j = 0; j < 4; ++j) {
            int o = p * 64 + w * 16 + (lane >> 4) * 4 + j;
            m4[((size_t)b * 256 + o) * N_ + colme] = am[p][j];
        }
        float s = ps[p], q = pq[p];
        #pragma unroll
        for (int off = 32; off > 0; off >>= 1) {
            s += __shfl_down(s, off);
            q += __shfl_down(q, off);
        }
        if (lane == 0) {
            int g = p * 4 + w;
            part[((b * 16 + g) * 2 + 0) * 256 + ntile] = s;
            part[((b * 16 + g) * 2 + 1) * 256 + ntile] = q;
        }
    }
}

// ---------------- GN4 finalize from deterministic partials ----------------
__global__ __launch_bounds__(256) void finalize4_kernel(const float* __restrict__ part,
    const float* __restrict__ gamma, const float* __restrict__ beta,
    float* __restrict__ ga, float* __restrict__ sh)
{
    int t = blockIdx.x * 256 + threadIdx.x;   // B*256
    if (t >= B_ * 256) return;
    int b = t >> 8, c = t & 255;
    int g = c >> 4;
    float sum = 0.f, sq = 0.f;
    for (int nt = 0; nt < 256; ++nt) {
        sum += part[((b * 16 + g) * 2 + 0) * 256 + nt];
        sq  += part[((b * 16 + g) * 2 + 1) * 256 + nt];
    }
    float cnt = 16.f * (float)NK_;
    float mean = sum / cnt;
    float var = fmaxf(sq / cnt - mean * mean, 0.f);
    float sc = gamma[c] * rsqrtf(var + EPS_);
    ga[t] = sc;
    sh[t] = beta[c] - mean * sc;
}

// ---------------- final: out = relu(a*max_k + s)  (valid since a>0) ----------------
__global__ __launch_bounds__(256) void apply_kernel(const float* __restrict__ m4,
    const float* __restrict__ ga, const float* __restrict__ sh, float* __restrict__ out)
{
    int t = blockIdx.x * 256 + threadIdx.x;   // b*256*N + c*N + n
    int bc = t >> 12;
    out[t] = fmaxf(fmaf(m4[t], ga[bc], sh[bc]), 0.f);
}

extern "C" void kernel_launch(void* const* d_in, const int* in_sizes, int n_in,
                              void* d_out, int out_size, void* d_ws, size_t ws_size,
                              hipStream_t stream)
{
    const float* pts = (const float*)d_in[0];
    const float* W1 = (const float*)d_in[1];
    const float* g1 = (const float*)d_in[2];
    const float* bt1 = (const float*)d_in[3];
    const float* W2 = (const float*)d_in[4];
    const float* g2 = (const float*)d_in[5];
    const float* bt2 = (const float*)d_in[6];
    const float* W3 = (const float*)d_in[7];
    const float* g3 = (const float*)d_in[8];
    const float* bt3 = (const float*)d_in[9];
    const float* W4 = (const float*)d_in[10];
    const float* g4 = (const float*)d_in[11];
    const float* bt4 = (const float*)d_in[12];
    float* out = (float*)d_out;

    char* ws = (char*)d_ws;
    size_t off = 0;
    auto alloc = [&](size_t bytes) -> void* {
        void* p = ws + off;
        off = (off + bytes + 255) & ~(size_t)255;
        return p;
    };
    int*   idx  = (int*)  alloc((size_t)B_ * NK_ * 4);           // 1.3 MB
    float* x0   = (float*)alloc((size_t)B_ * 13 * NK_ * 4);      // 17 MB
    unsigned short* y2g = (unsigned short*)alloc((size_t)B_ * 8 * NK_ * 8 * 2);   // 42 MB
    unsigned short* y3g = (unsigned short*)alloc((size_t)B_ * 16 * NK_ * 8 * 2);  // 84 MB
    float* m4   = (float*)alloc((size_t)B_ * 256 * N_ * 4);      // 16.8 MB
    bf16*  w3b  = (bf16*) alloc(128 * 64 * 2);                   // 16 KB
    bf16*  w4b  = (bf16*) alloc(256 * 128 * 2);                  // 64 KB
    float* p1   = (float*)alloc((size_t)B_ * NBLK_ * 32 * 4);    // 164 KB
    float* p2   = (float*)alloc((size_t)B_ * NBLK_ * 32 * 4);
    float* p3m  = (float*)alloc((size_t)B_ * 1024 * 32 * 4);     // 0.5 MB
    float* part4= (float*)alloc(4 * 16 * 2 * 256 * 4);           // 128 KB
    float* a1 = (float*)alloc(B_ * 64 * 4);
    float* s1 = (float*)alloc(B_ * 64 * 4);
    float* a2 = (float*)alloc(B_ * 64 * 4);
    float* s2 = (float*)alloc(B_ * 64 * 4);
    float* a3 = (float*)alloc(B_ * 128 * 4);
    float* s3 = (float*)alloc(B_ * 128 * 4);
    float* a4 = (float*)alloc(B_ * 256 * 4);
    float* s4 = (float*)alloc(B_ * 256 * 4);
    (void)ws_size; (void)in_sizes; (void)n_in; (void)out_size;

    knn_kernel<<<(B_ * N_) / 4, 256, 0, stream>>>(pts, idx);
    wcast_kernel<<<32, 256, 0, stream>>>(W3, w3b, 128 * 64);
    wcast_kernel<<<128, 256, 0, stream>>>(W4, w4b, 256 * 128);
    feature_kernel<<<(B_ * NK_) / 256, 256, 0, stream>>>(pts, idx, x0);

    stage1_kernel<<<dim3(NBLK_, B_), 256, 0, stream>>>(x0, W1, p1);
    finalize_kernel<64><<<1, 256, 0, stream>>>(p1, g1, bt1, a1, s1);

    stage2_kernel<<<dim3(NBLK_, B_), 256, 0, stream>>>(x0, W1, a1, s1, W2, y2g, p2);
    finalize_kernel<64><<<1, 256, 0, stream>>>(p2, g2, bt2, a2, s2);

    prep2_kernel<<<(int)(((size_t)B_ * 8 * NK_) / 256), 256, 0, stream>>>(y2g, a2, s2);
    stage3_mfma_kernel<<<dim3(N_ / 16, 1, B_), 256, 0, stream>>>((const short*)y2g, (const short*)w3b, y3g, p3m);
    finalize3_kernel<<<2, 256, 0, stream>>>(p3m, g3, bt3, a3, s3);

    prep4_kernel<<<(int)(((size_t)B_ * 16 * NK_) / 256), 256, 0, stream>>>(y3g, a3, s3);
    conv4_mfma_kernel<<<dim3(N_ / 16, 1, B_), 256, 0, stream>>>((const short*)y3g, (const short*)w4b, m4, part4);
    finalize4_kernel<<<4, 256, 0, stream>>>(part4, g4, bt4, a4, s4);

    apply_kernel<<<(B_ * 256 * N_) / 256, 256, 0, stream>>>(m4, a4, s4, out);
}

// Round 18
// 649.547 us; speedup vs baseline: 1.0652x; 1.0652x over previous
//
#include <hip/hip_runtime.h>
#include <hip/hip_bf16.h>
#include <math.h>

#define B_ 4
#define N_ 4096
#define K_ 20
#define NK_ (N_*K_)   // 81920
#define G_ 16
#define EPS_ 1e-5f
#define NBLK_ (NK_/256)   // 320 column-blocks per batch

typedef __hip_bfloat16 bf16;
typedef short bf16x8v __attribute__((ext_vector_type(8)));
typedef unsigned short u16x8v __attribute__((ext_vector_type(8)));
typedef unsigned short u16x4v __attribute__((ext_vector_type(4)));
typedef float f32x4v __attribute__((ext_vector_type(4)));

__device__ inline float b2f(bf16 v) { return __bfloat162float(v); }
__device__ inline bf16  f2b(float v){ return __float2bfloat16(v); }
__device__ inline float us2f(unsigned short u){ unsigned int i = ((unsigned)u) << 16; float f; __builtin_memcpy(&f, &i, 4); return f; }
__device__ inline unsigned short f2us(float f){ bf16 h = __float2bfloat16(f); unsigned short u; __builtin_memcpy(&u, &h, 2); return u; }

// ---------------- kNN: one WAVE per (b,i); linear arg-scan, -INF retire, no mask ----------------
// pd arithmetic bit-exact np (no FMA, sequential adds) — LOAD-BEARING, do not change.
// Rank 0 is always self (pd[i,i]=+0 strict max). Retired slots hold -INF (static-compare write,
// validated r17). Scan keeps r16 comparator (>= : largest c wins in-lane ties); butterfly larger-j.
__global__ __launch_bounds__(256) void knn_kernel(const float* __restrict__ pts, int* __restrict__ idx)
{
    int wid  = (blockIdx.x << 2) | (threadIdx.x >> 6);   // global wave id = b*N + i
    int lane = threadIdx.x & 63;
    int b = wid >> 12, i = wid & (N_ - 1);
    const float* pb = pts + (size_t)b * 6 * N_;
    float xi = pb[i], yi = pb[N_ + i], zi = pb[2 * N_ + i];
    float xxi = __fadd_rn(__fadd_rn(__fmul_rn(xi, xi), __fmul_rn(yi, yi)), __fmul_rn(zi, zi));
    float nxxi = -xxi;

    float pd[64];                    // candidate j = c*64 + lane (statically indexed only)
    #pragma unroll
    for (int c = 0; c < 64; ++c) {
        int j = c * 64 + lane;
        float xj = pb[j], yj = pb[N_ + j], zj = pb[2 * N_ + j];
        float xxj = __fadd_rn(__fadd_rn(__fmul_rn(xj, xj), __fmul_rn(yj, yj)), __fmul_rn(zj, zj));
        float px = __fmul_rn(xi, xj);
        float py = __fmul_rn(yi, yj);
        float pz = __fmul_rn(zi, zj);
        float dot = __fadd_rn(__fadd_rn(px, py), pz);   // NO FMA — matches np
        float inner = __fmul_rn(-2.0f, dot);
        pd[c] = __fsub_rn(__fsub_rn(nxxi, inner), xxj);
    }

    // rank 0 = self: emit and retire (pd[i,i] = +0 exactly; all others < 0)
    {
        int slot = __builtin_amdgcn_readfirstlane(i >> 6);
        int ln   = __builtin_amdgcn_readfirstlane(i & 63);
        bool me = (lane == ln);
        #pragma unroll
        for (int c = 0; c < 64; ++c)
            if (c == slot) pd[c] = me ? -INFINITY : pd[c];
        if (lane == 0) idx[(size_t)b * NK_ + i] = i;
    }

    for (int it = 1; it < K_; ++it) {
        // lane-local arg-scan, no mask (retired slots are -INF)
        float best = -INFINITY; int bc = 0;
        #pragma unroll
        for (int c = 0; c < 64; ++c)
            if (pd[c] >= best) { best = pd[c]; bc = c; }   // >=: largest c wins ties
        int bj = bc * 64 + lane;
        float bv = best;
        #pragma unroll
        for (int off = 1; off < 64; off <<= 1) {           // butterfly: all lanes converge
            float ov = __shfl_xor(bv, off);
            int   oj = __shfl_xor(bj, off);
            if (ov > bv || (ov == bv && oj > bj)) { bv = ov; bj = oj; }
        }
        if (lane == 0) idx[(size_t)b * NK_ + it * N_ + i] = bj;

        // retire exactly the winner: slot is wave-uniform -> scalar branch (validated r17)
        int slot = __builtin_amdgcn_readfirstlane(bj >> 6);
        int ln   = __builtin_amdgcn_readfirstlane(bj & 63);
        bool me = (lane == ln);
        #pragma unroll
        for (int c = 0; c < 64; ++c)
            if (c == slot) pd[c] = me ? -INFINITY : pd[c];
    }
}

// ---------------- angle: "x<0" quadrant predicate — LOAD-BEARING (round 10) ----------------
__device__ inline float angle3(float ax, float ay, float az, float bx, float by, float bz)
{
    float cx = __fsub_rn(__fmul_rn(ay, bz), __fmul_rn(az, by));
    float cy = __fsub_rn(__fmul_rn(az, bx), __fmul_rn(ax, bz));
    float cz = __fsub_rn(__fmul_rn(ax, by), __fmul_rn(ay, bx));
    float cn = sqrtf(__fadd_rn(__fadd_rn(__fmul_rn(cx, cx), __fmul_rn(cy, cy)), __fmul_rn(cz, cz)));
    float d  = __fadd_rn(__fadd_rn(__fmul_rn(ax, bx), __fmul_rn(ay, by)), __fmul_rn(az, bz));
    if (cn == 0.0f)
        return (d < 0.0f) ? 3.14159274101257324e+00f : 0.0f;   // -0 -> 0
    return atan2f(cn, d);
}

__global__ __launch_bounds__(256) void feature_kernel(const float* __restrict__ pts,
                                                      const int* __restrict__ idx,
                                                      float* __restrict__ x0)
{
    int t = blockIdx.x * 256 + threadIdx.x;           // [0, B*NK)
    int col = t % NK_;
    int b = t / NK_;
    int n = col & (N_ - 1);
    int j = idx[t];
    const float* pb = pts + (size_t)b * 6 * N_;
    float cx = pb[n],            cy = pb[N_ + n],     cz = pb[2 * N_ + n];
    float gx = pb[j],            gy = pb[N_ + j],     gz = pb[2 * N_ + j];
    float rx = pb[3 * N_ + n],   ry = pb[4 * N_ + n], rz = pb[5 * N_ + n];
    float ix = pb[3 * N_ + j],   iy = pb[4 * N_ + j], iz = pb[5 * N_ + j];
    float lx = __fsub_rn(gx, cx), ly = __fsub_rn(gy, cy), lz = __fsub_rn(gz, cz);

    float f9  = angle3(rx, ry, rz, lx, ly, lz);
    float f10 = angle3(ix, iy, iz, lx, ly, lz);
    float f11 = angle3(rx, ry, rz, ix, iy, iz);
    float f12 = sqrtf(__fadd_rn(__fadd_rn(__fmul_rn(lx, lx), __fmul_rn(ly, ly)), __fmul_rn(lz, lz)));

    float* xp = x0 + (size_t)b * 13 * NK_ + col;
    xp[0  * (size_t)NK_] = gx;
    xp[1  * (size_t)NK_] = gy;
    xp[2  * (size_t)NK_] = gz;
    xp[3  * (size_t)NK_] = cx;
    xp[4  * (size_t)NK_] = cy;
    xp[5  * (size_t)NK_] = cz;
    xp[6  * (size_t)NK_] = lx;
    xp[7  * (size_t)NK_] = ly;
    xp[8  * (size_t)NK_] = lz;
    xp[9  * (size_t)NK_] = f9;
    xp[10 * (size_t)NK_] = f10;
    xp[11 * (size_t)NK_] = f11;
    xp[12 * (size_t)NK_] = f12;
}

// ---------------- deterministic block reduction: 16 sums + 16 sumsqs -> 32 partials ----------------
__device__ inline void block_reduce_write(const float gsum[16], const float gsq[16], float* __restrict__ dst)
{
    __shared__ float red[4][32];
    int t = threadIdx.x, lane = t & 63, w = t >> 6;
    #pragma unroll
    for (int r = 0; r < 16; ++r) {
        float v = gsum[r];
        #pragma unroll
        for (int off = 32; off > 0; off >>= 1) v += __shfl_down(v, off);
        if (lane == 0) red[w][r] = v;
        float q = gsq[r];
        #pragma unroll
        for (int off = 32; off > 0; off >>= 1) q += __shfl_down(q, off);
        if (lane == 0) red[w][16 + r] = q;
    }
    __syncthreads();
    if (t < 32) dst[t] = red[0][t] + red[1][t] + red[2][t] + red[3][t];
}

// ---------------- stage1: conv1 -> GN1 partial stats (y1 never stored) ----------------
__global__ __launch_bounds__(256) void stage1_kernel(const float* __restrict__ x0,
    const float* __restrict__ W1, float* __restrict__ p1)
{
    int b = blockIdx.y;
    int col = blockIdx.x * 256 + threadIdx.x;
    const float* xb = x0 + (size_t)b * 13 * NK_ + col;
    float xr[13];
    #pragma unroll
    for (int c = 0; c < 13; ++c) xr[c] = xb[(size_t)c * NK_];
    float gsum[16], gsq[16];
    #pragma unroll
    for (int g = 0; g < 16; ++g) {
        float sg = 0.f, qg = 0.f;
        for (int oi = 0; oi < 4; ++oi) {
            int o = g * 4 + oi;
            float acc = 0.f;
            #pragma unroll
            for (int c = 0; c < 13; ++c) acc = fmaf(W1[o * 13 + c], xr[c], acc);
            sg += acc; qg += acc * acc;
        }
        gsum[g] = sg; gsq[g] = qg;
    }
    block_reduce_write(gsum, gsq, p1 + ((size_t)b * NBLK_ + blockIdx.x) * 32);
}

// ---------------- stage2: conv1+GN1+relu+conv2 -> y2g [b][cg=8][col][8c] + GN2 stats ----------------
__global__ __launch_bounds__(256) void stage2_kernel(const float* __restrict__ x0,
    const float* __restrict__ W1, const float* __restrict__ a1, const float* __restrict__ s1,
    const float* __restrict__ W2, unsigned short* __restrict__ y2g, float* __restrict__ p2)
{
    __shared__ float aL[64], sL[64];
    int b = blockIdx.y;
    int col = blockIdx.x * 256 + threadIdx.x;
    if (threadIdx.x < 64) {
        aL[threadIdx.x] = a1[b * 64 + threadIdx.x];
        sL[threadIdx.x] = s1[b * 64 + threadIdx.x];
    }
    __syncthreads();
    const float* xb = x0 + (size_t)b * 13 * NK_ + col;
    float xr[13];
    #pragma unroll
    for (int c = 0; c < 13; ++c) xr[c] = xb[(size_t)c * NK_];
    float y1r[64];
    #pragma unroll
    for (int o = 0; o < 64; ++o) {
        float acc = 0.f;
        #pragma unroll
        for (int c = 0; c < 13; ++c) acc = fmaf(W1[o * 13 + c], xr[c], acc);
        y1r[o] = fmaxf(fmaf(acc, aL[o], sL[o]), 0.f);
    }
    float gsum[16], gsq[16];
    #pragma unroll
    for (int r = 0; r < 16; ++r) { gsum[r] = 0.f; gsq[r] = 0.f; }
    #pragma unroll
    for (int og = 0; og < 8; ++og) {
        u16x8v row;
        #pragma unroll
        for (int oi = 0; oi < 8; ++oi) {
            int o = og * 8 + oi;
            float acc = 0.f;
            #pragma unroll
            for (int c = 0; c < 64; ++c) acc = fmaf(W2[o * 64 + c], y1r[c], acc);
            row[oi] = f2us(acc);
            gsum[og * 2 + (oi >> 2)] += acc;           // GN group o>>2, compile-time index
            gsq[og * 2 + (oi >> 2)] += acc * acc;      // stats on pre-rounding fp32
        }
        *reinterpret_cast<u16x8v*>(y2g + (((size_t)b * 8 + og) * NK_ + col) * 8) = row;
    }
    block_reduce_write(gsum, gsq, p2 + ((size_t)b * NBLK_ + blockIdx.x) * 32);
}

// ---------------- fold GN into per-(b,c) scale/shift: one WAVE per (b,c) ----------------
template<int COUT>
__global__ __launch_bounds__(256) void finalize_kernel(const float* __restrict__ part,
    const float* __restrict__ gamma, const float* __restrict__ beta,
    float* __restrict__ ga, float* __restrict__ sh)
{
    int wv = blockIdx.x * 4 + (threadIdx.x >> 6);   // wave id = b*COUT + c
    int lane = threadIdx.x & 63;
    int b = wv / COUT, c = wv % COUT;
    int g = c / (COUT / G_);
    float sum = 0.f, sq = 0.f;
    for (int blk = lane; blk < NBLK_; blk += 64) {
        const float* d = part + ((size_t)b * NBLK_ + blk) * 32;
        sum += d[g]; sq += d[16 + g];
    }
    #pragma unroll
    for (int off = 32; off > 0; off >>= 1) {
        sum += __shfl_down(sum, off);
        sq  += __shfl_down(sq, off);
    }
    if (lane == 0) {
        float cnt = (float)(COUT / G_) * (float)NK_;
        float mean = sum / cnt;
        float var = fmaxf(sq / cnt - mean * mean, 0.f);
        float sc = gamma[c] * rsqrtf(var + EPS_);
        ga[wv] = sc;
        sh[wv] = beta[c] - mean * sc;
    }
}

// ---------------- weight -> bf16 casts ----------------
__global__ __launch_bounds__(256) void wcast_kernel(const float* __restrict__ W, bf16* __restrict__ Wb, int n)
{
    int t = blockIdx.x * 256 + threadIdx.x;
    if (t < n) Wb[t] = f2b(W[t]);
}

// ---------------- prep2: in-place x2 = bf16(relu(a2*y2 + s2)) on y2g [b][cg=8][col][8c] ----------------
__global__ __launch_bounds__(256) void prep2_kernel(unsigned short* __restrict__ y2g,
    const float* __restrict__ a2, const float* __restrict__ s2)
{
    size_t t = (size_t)blockIdx.x * 256 + threadIdx.x;   // one (b,cg,col) 16B chunk
    int b  = (int)(t / ((size_t)8 * NK_));
    int cg = (int)((t / NK_) & 7);
    const float* ab = a2 + b * 64 + cg * 8;
    const float* sb = s2 + b * 64 + cg * 8;
    u16x8v v = *reinterpret_cast<const u16x8v*>(y2g + t * 8);
    #pragma unroll
    for (int j = 0; j < 8; ++j)
        v[j] = f2us(fmaxf(fmaf(us2f(v[j]), ab[j], sb[j]), 0.f));
    *reinterpret_cast<u16x8v*>(y2g + t * 8) = v;
}

// ---------------- stage3 via MFMA: y3 = W3 x x2 -> y3g grouped + GN3 partials ----------------
__global__ __launch_bounds__(256) void stage3_mfma_kernel(
    const short* __restrict__ x2g, const short* __restrict__ w3b,
    unsigned short* __restrict__ y3g, float* __restrict__ p3m)
{
    int ntile = blockIdx.x, b = blockIdx.z;
    int lane = threadIdx.x & 63, w = threadIdx.x >> 6;
    int colbase = ntile * 16 + (lane & 15);
    int cme = (lane >> 4) * 8;

    bf16x8v afr[8][2];
    #pragma unroll
    for (int ot = 0; ot < 8; ++ot)
        #pragma unroll
        for (int kb = 0; kb < 2; ++kb)
            afr[ot][kb] = *reinterpret_cast<const bf16x8v*>(
                w3b + (size_t)(ot * 16 + (lane & 15)) * 64 + kb * 32 + cme);

    float psum[8], psq[8];
    #pragma unroll
    for (int ot = 0; ot < 8; ++ot) { psum[ot] = 0.f; psq[ot] = 0.f; }

    for (int kk = 0; kk < 5; ++kk) {
        int k = kk * 4 + w;
        int colme = k * N_ + colbase;
        bf16x8v bfr[2];
        #pragma unroll
        for (int kb = 0; kb < 2; ++kb) {
            int cg = kb * 4 + (lane >> 4);
            bfr[kb] = *reinterpret_cast<const bf16x8v*>(
                x2g + (((size_t)b * 8 + cg) * NK_ + colme) * 8);
        }
        #pragma unroll
        for (int ot = 0; ot < 8; ++ot) {
            f32x4v acc = { 0.f, 0.f, 0.f, 0.f };
            acc = __builtin_amdgcn_mfma_f32_16x16x32_bf16(afr[ot][0], bfr[0], acc, 0, 0, 0);
            acc = __builtin_amdgcn_mfma_f32_16x16x32_bf16(afr[ot][1], bfr[1], acc, 0, 0, 0);
            u16x4v sv;
            #pragma unroll
            for (int j = 0; j < 4; ++j) {
                float v = acc[j];
                sv[j] = f2us(v);
                psum[ot] += v; psq[ot] += v * v;
            }
            int g = ot * 2 + (lane >> 5);
            *reinterpret_cast<u16x4v*>(
                y3g + (((size_t)b * 16 + g) * NK_ + colme) * 8 + ((lane >> 4) & 1) * 4) = sv;
        }
    }
    float* dst = p3m + ((size_t)(b * 256 + ntile) * 4 + w) * 32;
    #pragma unroll
    for (int ot = 0; ot < 8; ++ot) {
        float s = psum[ot], q = psq[ot];
        #pragma unroll
        for (int off = 16; off > 0; off >>= 1) {
            s += __shfl_down(s, off, 32);
            q += __shfl_down(q, off, 32);
        }
        if ((lane & 31) == 0) {
            int half = lane >> 5;
            dst[ot * 4 + half * 2 + 0] = s;
            dst[ot * 4 + half * 2 + 1] = q;
        }
    }
}

// ---------------- GN3 finalize: one WAVE per (b,c) over 1024 partial sets ----------------
__global__ __launch_bounds__(256) void finalize3_kernel(const float* __restrict__ p3m,
    const float* __restrict__ gamma, const float* __restrict__ beta,
    float* __restrict__ ga, float* __restrict__ sh)
{
    int wv = blockIdx.x * 4 + (threadIdx.x >> 6);   // 0..511 = b*128 + c
    int lane = threadIdx.x & 63;
    int b = wv >> 7, c = wv & 127;
    int g = c >> 3;
    int e = (g >> 1) * 4 + (g & 1) * 2;
    float sum = 0.f, sq = 0.f;
    for (int s = lane; s < 1024; s += 64) {
        const float* d = p3m + ((size_t)(b * 1024 + s)) * 32;
        sum += d[e]; sq += d[e + 1];
    }
    #pragma unroll
    for (int off = 32; off > 0; off >>= 1) {
        sum += __shfl_down(sum, off);
        sq  += __shfl_down(sq, off);
    }
    if (lane == 0) {
        float cnt = 8.f * (float)NK_;
        float mean = sum / cnt;
        float var = fmaxf(sq / cnt - mean * mean, 0.f);
        float sc = gamma[c] * rsqrtf(var + EPS_);
        ga[wv] = sc;
        sh[wv] = beta[c] - mean * sc;
    }
}

// ---------------- prep4: in-place x3 = bf16(relu(a3*y3 + s3)) on y3g [b][cg][col][8c] ----------------
__global__ __launch_bounds__(256) void prep4_kernel(unsigned short* __restrict__ y3g,
    const float* __restrict__ a3, const float* __restrict__ s3)
{
    size_t t = (size_t)blockIdx.x * 256 + threadIdx.x;   // one (b,cg,col) 16B chunk
    int b  = (int)(t / ((size_t)16 * NK_));
    int cg = (int)((t / NK_) & 15);
    const float* ab = a3 + b * 128 + cg * 8;
    const float* sb = s3 + b * 128 + cg * 8;
    u16x8v v = *reinterpret_cast<const u16x8v*>(y3g + t * 8);
    #pragma unroll
    for (int j = 0; j < 8; ++j)
        v[j] = f2us(fmaxf(fmaf(us2f(v[j]), ab[j], sb[j]), 0.f));
    *reinterpret_cast<u16x8v*>(y3g + t * 8) = v;
}

// ---------------- conv4 via MFMA: block = 16n tile, 4 waves x 4 o-passes = all 256 o ----------------
__global__ __launch_bounds__(256) void conv4_mfma_kernel(
    const short* __restrict__ x3g, const short* __restrict__ w4b,
    float* __restrict__ m4, float* __restrict__ part)
{
    int ntile = blockIdx.x, b = blockIdx.z;
    int lane = threadIdx.x & 63, w = threadIdx.x >> 6;
    int colme = ntile * 16 + (lane & 15);
    int cme = (lane >> 4) * 8;

    bf16x8v afr[4][4];
    #pragma unroll
    for (int p = 0; p < 4; ++p) {
        #pragma unroll
        for (int cb = 0; cb < 4; ++cb) {
            size_t aoff = (size_t)(p * 64 + w * 16 + (lane & 15)) * 128 + cb * 32 + cme;
            afr[p][cb] = *reinterpret_cast<const bf16x8v*>(w4b + aoff);
        }
    }

    float am[4][4];
    #pragma unroll
    for (int p = 0; p < 4; ++p)
        #pragma unroll
        for (int j = 0; j < 4; ++j) am[p][j] = -INFINITY;
    float ps[4] = {0.f, 0.f, 0.f, 0.f}, pq[4] = {0.f, 0.f, 0.f, 0.f};

    for (int k = 0; k < K_; ++k) {
        bf16x8v bfr[4];
        #pragma unroll
        for (int cb = 0; cb < 4; ++cb) {
            int cg = cb * 4 + (lane >> 4);
            bfr[cb] = *reinterpret_cast<const bf16x8v*>(
                x3g + (((size_t)b * 16 + cg) * NK_ + (size_t)k * N_ + colme) * 8);
        }
        #pragma unroll
        for (int p = 0; p < 4; ++p) {
            f32x4v acc = { 0.f, 0.f, 0.f, 0.f };
            #pragma unroll
            for (int cb = 0; cb < 4; ++cb)
                acc = __builtin_amdgcn_mfma_f32_16x16x32_bf16(afr[p][cb], bfr[cb], acc, 0, 0, 0);
            #pragma unroll
            for (int j = 0; j < 4; ++j) {
                float v = acc[j];
                am[p][j] = fmaxf(am[p][j], v);
                ps[p] += v; pq[p] += v * v;
            }
        }
    }
    #pragma unroll
    for (int p = 0; p < 4; ++p) {
        #pragma unroll
        for (int j = 0; j < 4; ++j) {
            int o = p * 64 + w * 16 + (lane >> 4) * 4 + j;
            m4[((size_t)b * 256 + o) * N_ + colme] = am[p][j];
        }
        float s = ps[p], q = pq[p];
        #pragma unroll
        for (int off = 32; off > 0; off >>= 1) {
            s += __shfl_down(s, off);
            q += __shfl_down(q, off);
        }
        if (lane == 0) {
            int g = p * 4 + w;
            part[((b * 16 + g) * 2 + 0) * 256 + ntile] = s;
            part[((b * 16 + g) * 2 + 1) * 256 + ntile] = q;
        }
    }
}

// ---------------- GN4 finalize: one WAVE per (b,c), coalesced 256-entry rows ----------------
__global__ __launch_bounds__(256) void finalize4_kernel(const float* __restrict__ part,
    const float* __restrict__ gamma, const float* __restrict__ beta,
    float* __restrict__ ga, float* __restrict__ sh)
{
    int wv = blockIdx.x * 4 + (threadIdx.x >> 6);   // 0..1023 = b*256 + c
    int lane = threadIdx.x & 63;
    int b = wv >> 8, c = wv & 255;
    int g = c >> 4;
    float sum = 0.f, sq = 0.f;
    for (int nt = lane; nt < 256; nt += 64) {
        sum += part[((b * 16 + g) * 2 + 0) * 256 + nt];
        sq  += part[((b * 16 + g) * 2 + 1) * 256 + nt];
    }
    #pragma unroll
    for (int off = 32; off > 0; off >>= 1) {
        sum += __shfl_down(sum, off);
        sq  += __shfl_down(sq, off);
    }
    if (lane == 0) {
        float cnt = 16.f * (float)NK_;
        float mean = sum / cnt;
        float var = fmaxf(sq / cnt - mean * mean, 0.f);
        float sc = gamma[c] * rsqrtf(var + EPS_);
        ga[wv] = sc;
        sh[wv] = beta[c] - mean * sc;
    }
}

// ---------------- final: out = relu(a*max_k + s)  (valid since a>0) ----------------
__global__ __launch_bounds__(256) void apply_kernel(const float* __restrict__ m4,
    const float* __restrict__ ga, const float* __restrict__ sh, float* __restrict__ out)
{
    int t = blockIdx.x * 256 + threadIdx.x;   // b*256*N + c*N + n
    int bc = t >> 12;
    out[t] = fmaxf(fmaf(m4[t], ga[bc], sh[bc]), 0.f);
}

extern "C" void kernel_launch(void* const* d_in, const int* in_sizes, int n_in,
                              void* d_out, int out_size, void* d_ws, size_t ws_size,
                              hipStream_t stream)
{
    const float* pts = (const float*)d_in[0];
    const float* W1 = (const float*)d_in[1];
    const float* g1 = (const float*)d_in[2];
    const float* bt1 = (const float*)d_in[3];
    const float* W2 = (const float*)d_in[4];
    const float* g2 = (const float*)d_in[5];
    const float* bt2 = (const float*)d_in[6];
    const float* W3 = (const float*)d_in[7];
    const float* g3 = (const float*)d_in[8];
    const float* bt3 = (const float*)d_in[9];
    const float* W4 = (const float*)d_in[10];
    const float* g4 = (const float*)d_in[11];
    const float* bt4 = (const float*)d_in[12];
    float* out = (float*)d_out;

    char* ws = (char*)d_ws;
    size_t off = 0;
    auto alloc = [&](size_t bytes) -> void* {
        void* p = ws + off;
        off = (off + bytes + 255) & ~(size_t)255;
        return p;
    };
    int*   idx  = (int*)  alloc((size_t)B_ * NK_ * 4);           // 1.3 MB
    float* x0   = (float*)alloc((size_t)B_ * 13 * NK_ * 4);      // 17 MB
    unsigned short* y2g = (unsigned short*)alloc((size_t)B_ * 8 * NK_ * 8 * 2);   // 42 MB
    unsigned short* y3g = (unsigned short*)alloc((size_t)B_ * 16 * NK_ * 8 * 2);  // 84 MB
    float* m4   = (float*)alloc((size_t)B_ * 256 * N_ * 4);      // 16.8 MB
    bf16*  w3b  = (bf16*) alloc(128 * 64 * 2);                   // 16 KB
    bf16*  w4b  = (bf16*) alloc(256 * 128 * 2);                  // 64 KB
    float* p1   = (float*)alloc((size_t)B_ * NBLK_ * 32 * 4);    // 164 KB
    float* p2   = (float*)alloc((size_t)B_ * NBLK_ * 32 * 4);
    float* p3m  = (float*)alloc((size_t)B_ * 1024 * 32 * 4);     // 0.5 MB
    float* part4= (float*)alloc(4 * 16 * 2 * 256 * 4);           // 128 KB
    float* a1 = (float*)alloc(B_ * 64 * 4);
    float* s1 = (float*)alloc(B_ * 64 * 4);
    float* a2 = (float*)alloc(B_ * 64 * 4);
    float* s2 = (float*)alloc(B_ * 64 * 4);
    float* a3 = (float*)alloc(B_ * 128 * 4);
    float* s3 = (float*)alloc(B_ * 128 * 4);
    float* a4 = (float*)alloc(B_ * 256 * 4);
    float* s4 = (float*)alloc(B_ * 256 * 4);
    (void)ws_size; (void)in_sizes; (void)n_in; (void)out_size;

    knn_kernel<<<(B_ * N_) / 4, 256, 0, stream>>>(pts, idx);
    wcast_kernel<<<32, 256, 0, stream>>>(W3, w3b, 128 * 64);
    wcast_kernel<<<128, 256, 0, stream>>>(W4, w4b, 256 * 128);
    feature_kernel<<<(B_ * NK_) / 256, 256, 0, stream>>>(pts, idx, x0);

    stage1_kernel<<<dim3(NBLK_, B_), 256, 0, stream>>>(x0, W1, p1);
    finalize_kernel<64><<<64, 256, 0, stream>>>(p1, g1, bt1, a1, s1);

    stage2_kernel<<<dim3(NBLK_, B_), 256, 0, stream>>>(x0, W1, a1, s1, W2, y2g, p2);
    finalize_kernel<64><<<64, 256, 0, stream>>>(p2, g2, bt2, a2, s2);

    prep2_kernel<<<(int)(((size_t)B_ * 8 * NK_) / 256), 256, 0, stream>>>(y2g, a2, s2);
    stage3_mfma_kernel<<<dim3(N_ / 16, 1, B_), 256, 0, stream>>>((const short*)y2g, (const short*)w3b, y3g, p3m);
    finalize3_kernel<<<128, 256, 0, stream>>>(p3m, g3, bt3, a3, s3);

    prep4_kernel<<<(int)(((size_t)B_ * 16 * NK_) / 256), 256, 0, stream>>>(y3g, a3, s3);
    conv4_mfma_kernel<<<dim3(N_ / 16, 1, B_), 256, 0, stream>>>((const short*)y3g, (const short*)w4b, m4, part4);
    finalize4_kernel<<<256, 256, 0, stream>>>(part4, g4, bt4, a4, s4);

    apply_kernel<<<(B_ * 256 * N_) / 256, 256, 0, stream>>>(m4, a4, s4, out);
}

// Round 19
// 511.079 us; speedup vs baseline: 1.3538x; 1.2709x over previous
//
#include <hip/hip_runtime.h>
#include <hip/hip_bf16.h>
#include <math.h>

#define B_ 4
#define N_ 4096
#define K_ 20
#define NK_ (N_*K_)   // 81920
#define G_ 16
#define EPS_ 1e-5f
#define NBLK_ (NK_/256)   // 320 column-blocks per batch

typedef __hip_bfloat16 bf16;
typedef short bf16x8v __attribute__((ext_vector_type(8)));
typedef unsigned short u16x8v __attribute__((ext_vector_type(8)));
typedef unsigned short u16x4v __attribute__((ext_vector_type(4)));
typedef float f32x4v __attribute__((ext_vector_type(4)));

__device__ inline float b2f(bf16 v) { return __bfloat162float(v); }
__device__ inline bf16  f2b(float v){ return __float2bfloat16(v); }
__device__ inline float us2f(unsigned short u){ unsigned int i = ((unsigned)u) << 16; float f; __builtin_memcpy(&f, &i, 4); return f; }
__device__ inline unsigned short f2us(float f){ bf16 h = __float2bfloat16(f); unsigned short u; __builtin_memcpy(&u, &h, 2); return u; }

// ---------------- kNN: one WAVE per (b,i); two-level cached selection ----------------
// pd arithmetic bit-exact np (no FMA, sequential adds) — LOAD-BEARING, do not change.
// Exact fp32 ties proven absent in this data (r3/r4 and r6/r8 bit-identical under both
// tie directions), so winner-lane choice via ballot-high is safe.
__global__ __launch_bounds__(256) void knn_kernel(const float* __restrict__ pts, int* __restrict__ idx)
{
    int wid  = (blockIdx.x << 2) | (threadIdx.x >> 6);   // global wave id = b*N + i
    int lane = threadIdx.x & 63;
    int b = wid >> 12, i = wid & (N_ - 1);
    const float* pb = pts + (size_t)b * 6 * N_;
    float xi = pb[i], yi = pb[N_ + i], zi = pb[2 * N_ + i];
    float xxi = __fadd_rn(__fadd_rn(__fmul_rn(xi, xi), __fmul_rn(yi, yi)), __fmul_rn(zi, zi));
    float nxxi = -xxi;

    float pd[64];                    // candidate j = c*64 + lane (statically indexed only)
    #pragma unroll
    for (int c = 0; c < 64; ++c) {
        int j = c * 64 + lane;
        float xj = pb[j], yj = pb[N_ + j], zj = pb[2 * N_ + j];
        float xxj = __fadd_rn(__fadd_rn(__fmul_rn(xj, xj), __fmul_rn(yj, yj)), __fmul_rn(zj, zj));
        float px = __fmul_rn(xi, xj);
        float py = __fmul_rn(yi, yj);
        float pz = __fmul_rn(zi, zj);
        float dot = __fadd_rn(__fadd_rn(px, py), pz);   // NO FMA — matches np
        float inner = __fmul_rn(-2.0f, dot);
        pd[c] = __fsub_rn(__fsub_rn(nxxi, inner), xxj);
    }

    // rank 0 = self: pd[i,i] = +0 exactly is the strict max; emit and retire
    {
        int slot = __builtin_amdgcn_readfirstlane(i >> 6);
        int ln   = __builtin_amdgcn_readfirstlane(i & 63);
        bool me = (lane == ln);
        #pragma unroll
        for (int c = 0; c < 64; ++c)
            if (c == slot) pd[c] = me ? -INFINITY : pd[c];
        if (lane == 0) idx[(size_t)b * NK_ + i] = i;
    }

    // persistent per-lane group maxima (8 groups x 8 slots)
    float gmax[8];
    #pragma unroll
    for (int g = 0; g < 8; ++g) {
        float m01 = fmaxf(pd[g * 8 + 0], pd[g * 8 + 1]);
        float m23 = fmaxf(pd[g * 8 + 2], pd[g * 8 + 3]);
        float m45 = fmaxf(pd[g * 8 + 4], pd[g * 8 + 5]);
        float m67 = fmaxf(pd[g * 8 + 6], pd[g * 8 + 7]);
        gmax[g] = fmaxf(fmaxf(m01, m23), fmaxf(m45, m67));
    }

    for (int it = 1; it < K_; ++it) {
        // lane max over 8 cached group maxima (7 ops, log depth)
        float a01 = fmaxf(gmax[0], gmax[1]);
        float a23 = fmaxf(gmax[2], gmax[3]);
        float a45 = fmaxf(gmax[4], gmax[5]);
        float a67 = fmaxf(gmax[6], gmax[7]);
        float vb = fmaxf(fmaxf(a01, a23), fmaxf(a45, a67));

        // wave max, value only (12 ops)
        float wv = vb;
        #pragma unroll
        for (int off = 1; off < 64; off <<= 1)
            wv = fmaxf(wv, __shfl_xor(wv, off));

        // winner lane = highest lane holding wv (ties absent)
        unsigned long long mk = __ballot(vb == wv);
        int wl = 63 - __builtin_clzll(mk);

        // winner's group (each lane scans its gmax; only winner's result used)
        int gsel = 0;
        #pragma unroll
        for (int g = 0; g < 8; ++g)
            if (gmax[g] == wv) gsel = g;
        int gw = __builtin_amdgcn_readfirstlane(__shfl(gsel, wl));

        // winner's slot within group gw (static branch: gw is SGPR)
        int usel = 0;
        #pragma unroll
        for (int g = 0; g < 8; ++g)
            if (g == gw) {
                #pragma unroll
                for (int u = 0; u < 8; ++u)
                    if (pd[g * 8 + u] == wv) usel = u;
            }
        int uw = __builtin_amdgcn_readfirstlane(__shfl(usel, wl));

        int bj = (gw * 8 + uw) * 64 + wl;
        if (lane == 0) idx[(size_t)b * NK_ + it * N_ + i] = bj;

        // retire winner slot + recompute only that group's max (static on gw,uw)
        bool me = (lane == wl);
        #pragma unroll
        for (int g = 0; g < 8; ++g)
            if (g == gw) {
                #pragma unroll
                for (int u = 0; u < 8; ++u)
                    if (u == uw) pd[g * 8 + u] = me ? -INFINITY : pd[g * 8 + u];
                float m01 = fmaxf(pd[g * 8 + 0], pd[g * 8 + 1]);
                float m23 = fmaxf(pd[g * 8 + 2], pd[g * 8 + 3]);
                float m45 = fmaxf(pd[g * 8 + 4], pd[g * 8 + 5]);
                float m67 = fmaxf(pd[g * 8 + 6], pd[g * 8 + 7]);
                gmax[g] = fmaxf(fmaxf(m01, m23), fmaxf(m45, m67));
            }
    }
}

// ---------------- angle: "x<0" quadrant predicate — LOAD-BEARING (round 10) ----------------
__device__ inline float angle3(float ax, float ay, float az, float bx, float by, float bz)
{
    float cx = __fsub_rn(__fmul_rn(ay, bz), __fmul_rn(az, by));
    float cy = __fsub_rn(__fmul_rn(az, bx), __fmul_rn(ax, bz));
    float cz = __fsub_rn(__fmul_rn(ax, by), __fmul_rn(ay, bx));
    float cn = sqrtf(__fadd_rn(__fadd_rn(__fmul_rn(cx, cx), __fmul_rn(cy, cy)), __fmul_rn(cz, cz)));
    float d  = __fadd_rn(__fadd_rn(__fmul_rn(ax, bx), __fmul_rn(ay, by)), __fmul_rn(az, bz));
    if (cn == 0.0f)
        return (d < 0.0f) ? 3.14159274101257324e+00f : 0.0f;   // -0 -> 0
    return atan2f(cn, d);
}

__global__ __launch_bounds__(256) void feature_kernel(const float* __restrict__ pts,
                                                      const int* __restrict__ idx,
                                                      float* __restrict__ x0)
{
    int t = blockIdx.x * 256 + threadIdx.x;           // [0, B*NK)
    int col = t % NK_;
    int b = t / NK_;
    int n = col & (N_ - 1);
    int j = idx[t];
    const float* pb = pts + (size_t)b * 6 * N_;
    float cx = pb[n],            cy = pb[N_ + n],     cz = pb[2 * N_ + n];
    float gx = pb[j],            gy = pb[N_ + j],     gz = pb[2 * N_ + j];
    float rx = pb[3 * N_ + n],   ry = pb[4 * N_ + n], rz = pb[5 * N_ + n];
    float ix = pb[3 * N_ + j],   iy = pb[4 * N_ + j], iz = pb[5 * N_ + j];
    float lx = __fsub_rn(gx, cx), ly = __fsub_rn(gy, cy), lz = __fsub_rn(gz, cz);

    float f9  = angle3(rx, ry, rz, lx, ly, lz);
    float f10 = angle3(ix, iy, iz, lx, ly, lz);
    float f11 = angle3(rx, ry, rz, ix, iy, iz);
    float f12 = sqrtf(__fadd_rn(__fadd_rn(__fmul_rn(lx, lx), __fmul_rn(ly, ly)), __fmul_rn(lz, lz)));

    float* xp = x0 + (size_t)b * 13 * NK_ + col;
    xp[0  * (size_t)NK_] = gx;
    xp[1  * (size_t)NK_] = gy;
    xp[2  * (size_t)NK_] = gz;
    xp[3  * (size_t)NK_] = cx;
    xp[4  * (size_t)NK_] = cy;
    xp[5  * (size_t)NK_] = cz;
    xp[6  * (size_t)NK_] = lx;
    xp[7  * (size_t)NK_] = ly;
    xp[8  * (size_t)NK_] = lz;
    xp[9  * (size_t)NK_] = f9;
    xp[10 * (size_t)NK_] = f10;
    xp[11 * (size_t)NK_] = f11;
    xp[12 * (size_t)NK_] = f12;
}

// ---------------- deterministic block reduction: 16 sums + 16 sumsqs -> 32 partials ----------------
__device__ inline void block_reduce_write(const float gsum[16], const float gsq[16], float* __restrict__ dst)
{
    __shared__ float red[4][32];
    int t = threadIdx.x, lane = t & 63, w = t >> 6;
    #pragma unroll
    for (int r = 0; r < 16; ++r) {
        float v = gsum[r];
        #pragma unroll
        for (int off = 32; off > 0; off >>= 1) v += __shfl_down(v, off);
        if (lane == 0) red[w][r] = v;
        float q = gsq[r];
        #pragma unroll
        for (int off = 32; off > 0; off >>= 1) q += __shfl_down(q, off);
        if (lane == 0) red[w][16 + r] = q;
    }
    __syncthreads();
    if (t < 32) dst[t] = red[0][t] + red[1][t] + red[2][t] + red[3][t];
}

// ---------------- stage1: conv1 -> GN1 partial stats (y1 never stored) ----------------
__global__ __launch_bounds__(256) void stage1_kernel(const float* __restrict__ x0,
    const float* __restrict__ W1, float* __restrict__ p1)
{
    int b = blockIdx.y;
    int col = blockIdx.x * 256 + threadIdx.x;
    const float* xb = x0 + (size_t)b * 13 * NK_ + col;
    float xr[13];
    #pragma unroll
    for (int c = 0; c < 13; ++c) xr[c] = xb[(size_t)c * NK_];
    float gsum[16], gsq[16];
    #pragma unroll
    for (int g = 0; g < 16; ++g) {
        float sg = 0.f, qg = 0.f;
        for (int oi = 0; oi < 4; ++oi) {
            int o = g * 4 + oi;
            float acc = 0.f;
            #pragma unroll
            for (int c = 0; c < 13; ++c) acc = fmaf(W1[o * 13 + c], xr[c], acc);
            sg += acc; qg += acc * acc;
        }
        gsum[g] = sg; gsq[g] = qg;
    }
    block_reduce_write(gsum, gsq, p1 + ((size_t)b * NBLK_ + blockIdx.x) * 32);
}

// ---------------- stage2: conv1+GN1+relu+conv2 -> y2g [b][cg=8][col][8c] + GN2 stats ----------------
__global__ __launch_bounds__(256) void stage2_kernel(const float* __restrict__ x0,
    const float* __restrict__ W1, const float* __restrict__ a1, const float* __restrict__ s1,
    const float* __restrict__ W2, unsigned short* __restrict__ y2g, float* __restrict__ p2)
{
    __shared__ float aL[64], sL[64];
    int b = blockIdx.y;
    int col = blockIdx.x * 256 + threadIdx.x;
    if (threadIdx.x < 64) {
        aL[threadIdx.x] = a1[b * 64 + threadIdx.x];
        sL[threadIdx.x] = s1[b * 64 + threadIdx.x];
    }
    __syncthreads();
    const float* xb = x0 + (size_t)b * 13 * NK_ + col;
    float xr[13];
    #pragma unroll
    for (int c = 0; c < 13; ++c) xr[c] = xb[(size_t)c * NK_];
    float y1r[64];
    #pragma unroll
    for (int o = 0; o < 64; ++o) {
        float acc = 0.f;
        #pragma unroll
        for (int c = 0; c < 13; ++c) acc = fmaf(W1[o * 13 + c], xr[c], acc);
        y1r[o] = fmaxf(fmaf(acc, aL[o], sL[o]), 0.f);
    }
    float gsum[16], gsq[16];
    #pragma unroll
    for (int r = 0; r < 16; ++r) { gsum[r] = 0.f; gsq[r] = 0.f; }
    #pragma unroll
    for (int og = 0; og < 8; ++og) {
        u16x8v row;
        #pragma unroll
        for (int oi = 0; oi < 8; ++oi) {
            int o = og * 8 + oi;
            float acc = 0.f;
            #pragma unroll
            for (int c = 0; c < 64; ++c) acc = fmaf(W2[o * 64 + c], y1r[c], acc);
            row[oi] = f2us(acc);
            gsum[og * 2 + (oi >> 2)] += acc;           // GN group o>>2, compile-time index
            gsq[og * 2 + (oi >> 2)] += acc * acc;      // stats on pre-rounding fp32
        }
        *reinterpret_cast<u16x8v*>(y2g + (((size_t)b * 8 + og) * NK_ + col) * 8) = row;
    }
    block_reduce_write(gsum, gsq, p2 + ((size_t)b * NBLK_ + blockIdx.x) * 32);
}

// ---------------- fold GN into per-(b,c) scale/shift: one WAVE per (b,c) ----------------
template<int COUT>
__global__ __launch_bounds__(256) void finalize_kernel(const float* __restrict__ part,
    const float* __restrict__ gamma, const float* __restrict__ beta,
    float* __restrict__ ga, float* __restrict__ sh)
{
    int wv = blockIdx.x * 4 + (threadIdx.x >> 6);   // wave id = b*COUT + c
    int lane = threadIdx.x & 63;
    int b = wv / COUT, c = wv % COUT;
    int g = c / (COUT / G_);
    float sum = 0.f, sq = 0.f;
    for (int blk = lane; blk < NBLK_; blk += 64) {
        const float* d = part + ((size_t)b * NBLK_ + blk) * 32;
        sum += d[g]; sq += d[16 + g];
    }
    #pragma unroll
    for (int off = 32; off > 0; off >>= 1) {
        sum += __shfl_down(sum, off);
        sq  += __shfl_down(sq, off);
    }
    if (lane == 0) {
        float cnt = (float)(COUT / G_) * (float)NK_;
        float mean = sum / cnt;
        float var = fmaxf(sq / cnt - mean * mean, 0.f);
        float sc = gamma[c] * rsqrtf(var + EPS_);
        ga[wv] = sc;
        sh[wv] = beta[c] - mean * sc;
    }
}

// ---------------- weight -> bf16 casts ----------------
__global__ __launch_bounds__(256) void wcast_kernel(const float* __restrict__ W, bf16* __restrict__ Wb, int n)
{
    int t = blockIdx.x * 256 + threadIdx.x;
    if (t < n) Wb[t] = f2b(W[t]);
}

// ---------------- prep2: in-place x2 = bf16(relu(a2*y2 + s2)) on y2g [b][cg=8][col][8c] ----------------
__global__ __launch_bounds__(256) void prep2_kernel(unsigned short* __restrict__ y2g,
    const float* __restrict__ a2, const float* __restrict__ s2)
{
    size_t t = (size_t)blockIdx.x * 256 + threadIdx.x;   // one (b,cg,col) 16B chunk
    int b  = (int)(t / ((size_t)8 * NK_));
    int cg = (int)((t / NK_) & 7);
    const float* ab = a2 + b * 64 + cg * 8;
    const float* sb = s2 + b * 64 + cg * 8;
    u16x8v v = *reinterpret_cast<const u16x8v*>(y2g + t * 8);
    #pragma unroll
    for (int j = 0; j < 8; ++j)
        v[j] = f2us(fmaxf(fmaf(us2f(v[j]), ab[j], sb[j]), 0.f));
    *reinterpret_cast<u16x8v*>(y2g + t * 8) = v;
}

// ---------------- stage3 via MFMA: y3 = W3 x x2 -> y3g grouped + GN3 partials ----------------
__global__ __launch_bounds__(256) void stage3_mfma_kernel(
    const short* __restrict__ x2g, const short* __restrict__ w3b,
    unsigned short* __restrict__ y3g, float* __restrict__ p3m)
{
    int ntile = blockIdx.x, b = blockIdx.z;
    int lane = threadIdx.x & 63, w = threadIdx.x >> 6;
    int colbase = ntile * 16 + (lane & 15);
    int cme = (lane >> 4) * 8;

    bf16x8v afr[8][2];
    #pragma unroll
    for (int ot = 0; ot < 8; ++ot)
        #pragma unroll
        for (int kb = 0; kb < 2; ++kb)
            afr[ot][kb] = *reinterpret_cast<const bf16x8v*>(
                w3b + (size_t)(ot * 16 + (lane & 15)) * 64 + kb * 32 + cme);

    float psum[8], psq[8];
    #pragma unroll
    for (int ot = 0; ot < 8; ++ot) { psum[ot] = 0.f; psq[ot] = 0.f; }

    for (int kk = 0; kk < 5; ++kk) {
        int k = kk * 4 + w;
        int colme = k * N_ + colbase;
        bf16x8v bfr[2];
        #pragma unroll
        for (int kb = 0; kb < 2; ++kb) {
            int cg = kb * 4 + (lane >> 4);
            bfr[kb] = *reinterpret_cast<const bf16x8v*>(
                x2g + (((size_t)b * 8 + cg) * NK_ + colme) * 8);
        }
        #pragma unroll
        for (int ot = 0; ot < 8; ++ot) {
            f32x4v acc = { 0.f, 0.f, 0.f, 0.f };
            acc = __builtin_amdgcn_mfma_f32_16x16x32_bf16(afr[ot][0], bfr[0], acc, 0, 0, 0);
            acc = __builtin_amdgcn_mfma_f32_16x16x32_bf16(afr[ot][1], bfr[1], acc, 0, 0, 0);
            u16x4v sv;
            #pragma unroll
            for (int j = 0; j < 4; ++j) {
                float v = acc[j];
                sv[j] = f2us(v);
                psum[ot] += v; psq[ot] += v * v;
            }
            int g = ot * 2 + (lane >> 5);
            *reinterpret_cast<u16x4v*>(
                y3g + (((size_t)b * 16 + g) * NK_ + colme) * 8 + ((lane >> 4) & 1) * 4) = sv;
        }
    }
    float* dst = p3m + ((size_t)(b * 256 + ntile) * 4 + w) * 32;
    #pragma unroll
    for (int ot = 0; ot < 8; ++ot) {
        float s = psum[ot], q = psq[ot];
        #pragma unroll
        for (int off = 16; off > 0; off >>= 1) {
            s += __shfl_down(s, off, 32);
            q += __shfl_down(q, off, 32);
        }
        if ((lane & 31) == 0) {
            int half = lane >> 5;
            dst[ot * 4 + half * 2 + 0] = s;
            dst[ot * 4 + half * 2 + 1] = q;
        }
    }
}

// ---------------- GN3 finalize: one WAVE per (b,c) over 1024 partial sets ----------------
__global__ __launch_bounds__(256) void finalize3_kernel(const float* __restrict__ p3m,
    const float* __restrict__ gamma, const float* __restrict__ beta,
    float* __restrict__ ga, float* __restrict__ sh)
{
    int wv = blockIdx.x * 4 + (threadIdx.x >> 6);   // 0..511 = b*128 + c
    int lane = threadIdx.x & 63;
    int b = wv >> 7, c = wv & 127;
    int g = c >> 3;
    int e = (g >> 1) * 4 + (g & 1) * 2;
    float sum = 0.f, sq = 0.f;
    for (int s = lane; s < 1024; s += 64) {
        const float* d = p3m + ((size_t)(b * 1024 + s)) * 32;
        sum += d[e]; sq += d[e + 1];
    }
    #pragma unroll
    for (int off = 32; off > 0; off >>= 1) {
        sum += __shfl_down(sum, off);
        sq  += __shfl_down(sq, off);
    }
    if (lane == 0) {
        float cnt = 8.f * (float)NK_;
        float mean = sum / cnt;
        float var = fmaxf(sq / cnt - mean * mean, 0.f);
        float sc = gamma[c] * rsqrtf(var + EPS_);
        ga[wv] = sc;
        sh[wv] = beta[c] - mean * sc;
    }
}

// ---------------- prep4: in-place x3 = bf16(relu(a3*y3 + s3)) on y3g [b][cg][col][8c] ----------------
__global__ __launch_bounds__(256) void prep4_kernel(unsigned short* __restrict__ y3g,
    const float* __restrict__ a3, const float* __restrict__ s3)
{
    size_t t = (size_t)blockIdx.x * 256 + threadIdx.x;   // one (b,cg,col) 16B chunk
    int b  = (int)(t / ((size_t)16 * NK_));
    int cg = (int)((t / NK_) & 15);
    const float* ab = a3 + b * 128 + cg * 8;
    const float* sb = s3 + b * 128 + cg * 8;
    u16x8v v = *reinterpret_cast<const u16x8v*>(y3g + t * 8);
    #pragma unroll
    for (int j = 0; j < 8; ++j)
        v[j] = f2us(fmaxf(fmaf(us2f(v[j]), ab[j], sb[j]), 0.f));
    *reinterpret_cast<u16x8v*>(y3g + t * 8) = v;
}

// ---------------- conv4 via MFMA: block = 16n tile, 4 waves x 4 o-passes = all 256 o ----------------
__global__ __launch_bounds__(256) void conv4_mfma_kernel(
    const short* __restrict__ x3g, const short* __restrict__ w4b,
    float* __restrict__ m4, float* __restrict__ part)
{
    int ntile = blockIdx.x, b = blockIdx.z;
    int lane = threadIdx.x & 63, w = threadIdx.x >> 6;
    int colme = ntile * 16 + (lane & 15);
    int cme = (lane >> 4) * 8;

    bf16x8v afr[4][4];
    #pragma unroll
    for (int p = 0; p < 4; ++p) {
        #pragma unroll
        for (int cb = 0; cb < 4; ++cb) {
            size_t aoff = (size_t)(p * 64 + w * 16 + (lane & 15)) * 128 + cb * 32 + cme;
            afr[p][cb] = *reinterpret_cast<const bf16x8v*>(w4b + aoff);
        }
    }

    float am[4][4];
    #pragma unroll
    for (int p = 0; p < 4; ++p)
        #pragma unroll
        for (int j = 0; j < 4; ++j) am[p][j] = -INFINITY;
    float ps[4] = {0.f, 0.f, 0.f, 0.f}, pq[4] = {0.f, 0.f, 0.f, 0.f};

    for (int k = 0; k < K_; ++k) {
        bf16x8v bfr[4];
        #pragma unroll
        for (int cb = 0; cb < 4; ++cb) {
            int cg = cb * 4 + (lane >> 4);
            bfr[cb] = *reinterpret_cast<const bf16x8v*>(
                x3g + (((size_t)b * 16 + cg) * NK_ + (size_t)k * N_ + colme) * 8);
        }
        #pragma unroll
        for (int p = 0; p < 4; ++p) {
            f32x4v acc = { 0.f, 0.f, 0.f, 0.f };
            #pragma unroll
            for (int cb = 0; cb < 4; ++cb)
                acc = __builtin_amdgcn_mfma_f32_16x16x32_bf16(afr[p][cb], bfr[cb], acc, 0, 0, 0);
            #pragma unroll
            for (int j = 0; j < 4; ++j) {
                float v = acc[j];
                am[p][j] = fmaxf(am[p][j], v);
                ps[p] += v; pq[p] += v * v;
            }
        }
    }
    #pragma unroll
    for (int p = 0; p < 4; ++p) {
        #pragma unroll
        for (int j = 0; j < 4; ++j) {
            int o = p * 64 + w * 16 + (lane >> 4) * 4 + j;
            m4[((size_t)b * 256 + o) * N_ + colme] = am[p][j];
        }
        float s = ps[p], q = pq[p];
        #pragma unroll
        for (int off = 32; off > 0; off >>= 1) {
            s += __shfl_down(s, off);
            q += __shfl_down(q, off);
        }
        if (lane == 0) {
            int g = p * 4 + w;
            part[((b * 16 + g) * 2 + 0) * 256 + ntile] = s;
            part[((b * 16 + g) * 2 + 1) * 256 + ntile] = q;
        }
    }
}

// ---------------- GN4 finalize: one WAVE per (b,c), coalesced 256-entry rows ----------------
__global__ __launch_bounds__(256) void finalize4_kernel(const float* __restrict__ part,
    const float* __restrict__ gamma, const float* __restrict__ beta,
    float* __restrict__ ga, float* __restrict__ sh)
{
    int wv = blockIdx.x * 4 + (threadIdx.x >> 6);   // 0..1023 = b*256 + c
    int lane = threadIdx.x & 63;
    int b = wv >> 8, c = wv & 255;
    int g = c >> 4;
    float sum = 0.f, sq = 0.f;
    for (int nt = lane; nt < 256; nt += 64) {
        sum += part[((b * 16 + g) * 2 + 0) * 256 + nt];
        sq  += part[((b * 16 + g) * 2 + 1) * 256 + nt];
    }
    #pragma unroll
    for (int off = 32; off > 0; off >>= 1) {
        sum += __shfl_down(sum, off);
        sq  += __shfl_down(sq, off);
    }
    if (lane == 0) {
        float cnt = 16.f * (float)NK_;
        float mean = sum / cnt;
        float var = fmaxf(sq / cnt - mean * mean, 0.f);
        float sc = gamma[c] * rsqrtf(var + EPS_);
        ga[wv] = sc;
        sh[wv] = beta[c] - mean * sc;
    }
}

// ---------------- final: out = relu(a*max_k + s)  (valid since a>0) ----------------
__global__ __launch_bounds__(256) void apply_kernel(const float* __restrict__ m4,
    const float* __restrict__ ga, const float* __restrict__ sh, float* __restrict__ out)
{
    int t = blockIdx.x * 256 + threadIdx.x;   // b*256*N + c*N + n
    int bc = t >> 12;
    out[t] = fmaxf(fmaf(m4[t], ga[bc], sh[bc]), 0.f);
}

extern "C" void kernel_launch(void* const* d_in, const int* in_sizes, int n_in,
                              void* d_out, int out_size, void* d_ws, size_t ws_size,
                              hipStream_t stream)
{
    const float* pts = (const float*)d_in[0];
    const float* W1 = (const float*)d_in[1];
    const float* g1 = (const float*)d_in[2];
    const float* bt1 = (const float*)d_in[3];
    const float* W2 = (const float*)d_in[4];
    const float* g2 = (const float*)d_in[5];
    const float* bt2 = (const float*)d_in[6];
    const float* W3 = (const float*)d_in[7];
    const float* g3 = (const float*)d_in[8];
    const float* bt3 = (const float*)d_in[9];
    const float* W4 = (const float*)d_in[10];
    const float* g4 = (const float*)d_in[11];
    const float* bt4 = (const float*)d_in[12];
    float* out = (float*)d_out;

    char* ws = (char*)d_ws;
    size_t off = 0;
    auto alloc = [&](size_t bytes) -> void* {
        void* p = ws + off;
        off = (off + bytes + 255) & ~(size_t)255;
        return p;
    };
    int*   idx  = (int*)  alloc((size_t)B_ * NK_ * 4);           // 1.3 MB
    float* x0   = (float*)alloc((size_t)B_ * 13 * NK_ * 4);      // 17 MB
    unsigned short* y2g = (unsigned short*)alloc((size_t)B_ * 8 * NK_ * 8 * 2);   // 42 MB
    unsigned short* y3g = (unsigned short*)alloc((size_t)B_ * 16 * NK_ * 8 * 2);  // 84 MB
    float* m4   = (float*)alloc((size_t)B_ * 256 * N_ * 4);      // 16.8 MB
    bf16*  w3b  = (bf16*) alloc(128 * 64 * 2);                   // 16 KB
    bf16*  w4b  = (bf16*) alloc(256 * 128 * 2);                  // 64 KB
    float* p1   = (float*)alloc((size_t)B_ * NBLK_ * 32 * 4);    // 164 KB
    float* p2   = (float*)alloc((size_t)B_ * NBLK_ * 32 * 4);
    float* p3m  = (float*)alloc((size_t)B_ * 1024 * 32 * 4);     // 0.5 MB
    float* part4= (float*)alloc(4 * 16 * 2 * 256 * 4);           // 128 KB
    float* a1 = (float*)alloc(B_ * 64 * 4);
    float* s1 = (float*)alloc(B_ * 64 * 4);
    float* a2 = (float*)alloc(B_ * 64 * 4);
    float* s2 = (float*)alloc(B_ * 64 * 4);
    float* a3 = (float*)alloc(B_ * 128 * 4);
    float* s3 = (float*)alloc(B_ * 128 * 4);
    float* a4 = (float*)alloc(B_ * 256 * 4);
    float* s4 = (float*)alloc(B_ * 256 * 4);
    (void)ws_size; (void)in_sizes; (void)n_in; (void)out_size;

    knn_kernel<<<(B_ * N_) / 4, 256, 0, stream>>>(pts, idx);
    wcast_kernel<<<32, 256, 0, stream>>>(W3, w3b, 128 * 64);
    wcast_kernel<<<128, 256, 0, stream>>>(W4, w4b, 256 * 128);
    feature_kernel<<<(B_ * NK_) / 256, 256, 0, stream>>>(pts, idx, x0);

    stage1_kernel<<<dim3(NBLK_, B_), 256, 0, stream>>>(x0, W1, p1);
    finalize_kernel<64><<<64, 256, 0, stream>>>(p1, g1, bt1, a1, s1);

    stage2_kernel<<<dim3(NBLK_, B_), 256, 0, stream>>>(x0, W1, a1, s1, W2, y2g, p2);
    finalize_kernel<64><<<64, 256, 0, stream>>>(p2, g2, bt2, a2, s2);

    prep2_kernel<<<(int)(((size_t)B_ * 8 * NK_) / 256), 256, 0, stream>>>(y2g, a2, s2);
    stage3_mfma_kernel<<<dim3(N_ / 16, 1, B_), 256, 0, stream>>>((const short*)y2g, (const short*)w3b, y3g, p3m);
    finalize3_kernel<<<128, 256, 0, stream>>>(p3m, g3, bt3, a3, s3);

    prep4_kernel<<<(int)(((size_t)B_ * 16 * NK_) / 256), 256, 0, stream>>>(y3g, a3, s3);
    conv4_mfma_kernel<<<dim3(N_ / 16, 1, B_), 256, 0, stream>>>((const short*)y3g, (const short*)w4b, m4, part4);
    finalize4_kernel<<<256, 256, 0, stream>>>(part4, g4, bt4, a4, s4);

    apply_kernel<<<(B_ * 256 * N_) / 256, 256, 0, stream>>>(m4, a4, s4, out);
}

// Round 20
// 375.424 us; speedup vs baseline: 1.8430x; 1.3613x over previous
//
#include <hip/hip_runtime.h>
#include <hip/hip_bf16.h>
#include <math.h>

#define B_ 4
#define N_ 4096
#define K_ 20
#define NK_ (N_*K_)   // 81920
#define G_ 16
#define EPS_ 1e-5f
#define NBLK_ (NK_/256)   // 320 column-blocks per batch

typedef __hip_bfloat16 bf16;
typedef short bf16x8v __attribute__((ext_vector_type(8)));
typedef unsigned short u16x8v __attribute__((ext_vector_type(8)));
typedef unsigned short u16x4v __attribute__((ext_vector_type(4)));
typedef float f32x4v __attribute__((ext_vector_type(4)));

__device__ inline float b2f(bf16 v) { return __bfloat162float(v); }
__device__ inline bf16  f2b(float v){ return __float2bfloat16(v); }
__device__ inline float us2f(unsigned short u){ unsigned int i = ((unsigned)u) << 16; float f; __builtin_memcpy(&f, &i, 4); return f; }
__device__ inline unsigned short f2us(float f){ bf16 h = __float2bfloat16(f); unsigned short u; __builtin_memcpy(&u, &h, 2); return u; }

// ---------------- kNN: one WAVE per (b,i); two-level cached selection (r19 WIN) ----------------
// pd arithmetic bit-exact np (no FMA, sequential adds) — LOAD-BEARING, do not change.
__global__ __launch_bounds__(256) void knn_kernel(const float* __restrict__ pts, int* __restrict__ idx)
{
    int wid  = (blockIdx.x << 2) | (threadIdx.x >> 6);   // global wave id = b*N + i
    int lane = threadIdx.x & 63;
    int b = wid >> 12, i = wid & (N_ - 1);
    const float* pb = pts + (size_t)b * 6 * N_;
    float xi = pb[i], yi = pb[N_ + i], zi = pb[2 * N_ + i];
    float xxi = __fadd_rn(__fadd_rn(__fmul_rn(xi, xi), __fmul_rn(yi, yi)), __fmul_rn(zi, zi));
    float nxxi = -xxi;

    float pd[64];                    // candidate j = c*64 + lane (statically indexed only)
    #pragma unroll
    for (int c = 0; c < 64; ++c) {
        int j = c * 64 + lane;
        float xj = pb[j], yj = pb[N_ + j], zj = pb[2 * N_ + j];
        float xxj = __fadd_rn(__fadd_rn(__fmul_rn(xj, xj), __fmul_rn(yj, yj)), __fmul_rn(zj, zj));
        float px = __fmul_rn(xi, xj);
        float py = __fmul_rn(yi, yj);
        float pz = __fmul_rn(zi, zj);
        float dot = __fadd_rn(__fadd_rn(px, py), pz);   // NO FMA — matches np
        float inner = __fmul_rn(-2.0f, dot);
        pd[c] = __fsub_rn(__fsub_rn(nxxi, inner), xxj);
    }

    // rank 0 = self: pd[i,i] = +0 exactly is the strict max; emit and retire
    {
        int slot = __builtin_amdgcn_readfirstlane(i >> 6);
        int ln   = __builtin_amdgcn_readfirstlane(i & 63);
        bool me = (lane == ln);
        #pragma unroll
        for (int c = 0; c < 64; ++c)
            if (c == slot) pd[c] = me ? -INFINITY : pd[c];
        if (lane == 0) idx[(size_t)b * NK_ + i] = i;
    }

    float gmax[8];
    #pragma unroll
    for (int g = 0; g < 8; ++g) {
        float m01 = fmaxf(pd[g * 8 + 0], pd[g * 8 + 1]);
        float m23 = fmaxf(pd[g * 8 + 2], pd[g * 8 + 3]);
        float m45 = fmaxf(pd[g * 8 + 4], pd[g * 8 + 5]);
        float m67 = fmaxf(pd[g * 8 + 6], pd[g * 8 + 7]);
        gmax[g] = fmaxf(fmaxf(m01, m23), fmaxf(m45, m67));
    }

    for (int it = 1; it < K_; ++it) {
        float a01 = fmaxf(gmax[0], gmax[1]);
        float a23 = fmaxf(gmax[2], gmax[3]);
        float a45 = fmaxf(gmax[4], gmax[5]);
        float a67 = fmaxf(gmax[6], gmax[7]);
        float vb = fmaxf(fmaxf(a01, a23), fmaxf(a45, a67));

        float wv = vb;
        #pragma unroll
        for (int off = 1; off < 64; off <<= 1)
            wv = fmaxf(wv, __shfl_xor(wv, off));

        unsigned long long mk = __ballot(vb == wv);
        int wl = 63 - __builtin_clzll(mk);

        int gsel = 0;
        #pragma unroll
        for (int g = 0; g < 8; ++g)
            if (gmax[g] == wv) gsel = g;
        int gw = __builtin_amdgcn_readfirstlane(__shfl(gsel, wl));

        int usel = 0;
        #pragma unroll
        for (int g = 0; g < 8; ++g)
            if (g == gw) {
                #pragma unroll
                for (int u = 0; u < 8; ++u)
                    if (pd[g * 8 + u] == wv) usel = u;
            }
        int uw = __builtin_amdgcn_readfirstlane(__shfl(usel, wl));

        int bj = (gw * 8 + uw) * 64 + wl;
        if (lane == 0) idx[(size_t)b * NK_ + it * N_ + i] = bj;

        bool me = (lane == wl);
        #pragma unroll
        for (int g = 0; g < 8; ++g)
            if (g == gw) {
                #pragma unroll
                for (int u = 0; u < 8; ++u)
                    if (u == uw) pd[g * 8 + u] = me ? -INFINITY : pd[g * 8 + u];
                float m01 = fmaxf(pd[g * 8 + 0], pd[g * 8 + 1]);
                float m23 = fmaxf(pd[g * 8 + 2], pd[g * 8 + 3]);
                float m45 = fmaxf(pd[g * 8 + 4], pd[g * 8 + 5]);
                float m67 = fmaxf(pd[g * 8 + 6], pd[g * 8 + 7]);
                gmax[g] = fmaxf(fmaxf(m01, m23), fmaxf(m45, m67));
            }
    }
}

// ---------------- angle: "x<0" quadrant predicate — LOAD-BEARING (round 10) ----------------
__device__ inline float angle3(float ax, float ay, float az, float bx, float by, float bz)
{
    float cx = __fsub_rn(__fmul_rn(ay, bz), __fmul_rn(az, by));
    float cy = __fsub_rn(__fmul_rn(az, bx), __fmul_rn(ax, bz));
    float cz = __fsub_rn(__fmul_rn(ax, by), __fmul_rn(ay, bx));
    float cn = sqrtf(__fadd_rn(__fadd_rn(__fmul_rn(cx, cx), __fmul_rn(cy, cy)), __fmul_rn(cz, cz)));
    float d  = __fadd_rn(__fadd_rn(__fmul_rn(ax, bx), __fmul_rn(ay, by)), __fmul_rn(az, bz));
    if (cn == 0.0f)
        return (d < 0.0f) ? 3.14159274101257324e+00f : 0.0f;   // -0 -> 0
    return atan2f(cn, d);
}

__global__ __launch_bounds__(256) void feature_kernel(const float* __restrict__ pts,
                                                      const int* __restrict__ idx,
                                                      float* __restrict__ x0)
{
    int t = blockIdx.x * 256 + threadIdx.x;           // [0, B*NK)
    int col = t % NK_;
    int b = t / NK_;
    int n = col & (N_ - 1);
    int j = idx[t];
    const float* pb = pts + (size_t)b * 6 * N_;
    float cx = pb[n],            cy = pb[N_ + n],     cz = pb[2 * N_ + n];
    float gx = pb[j],            gy = pb[N_ + j],     gz = pb[2 * N_ + j];
    float rx = pb[3 * N_ + n],   ry = pb[4 * N_ + n], rz = pb[5 * N_ + n];
    float ix = pb[3 * N_ + j],   iy = pb[4 * N_ + j], iz = pb[5 * N_ + j];
    float lx = __fsub_rn(gx, cx), ly = __fsub_rn(gy, cy), lz = __fsub_rn(gz, cz);

    float f9  = angle3(rx, ry, rz, lx, ly, lz);
    float f10 = angle3(ix, iy, iz, lx, ly, lz);
    float f11 = angle3(rx, ry, rz, ix, iy, iz);
    float f12 = sqrtf(__fadd_rn(__fadd_rn(__fmul_rn(lx, lx), __fmul_rn(ly, ly)), __fmul_rn(lz, lz)));

    float* xp = x0 + (size_t)b * 13 * NK_ + col;
    xp[0  * (size_t)NK_] = gx;
    xp[1  * (size_t)NK_] = gy;
    xp[2  * (size_t)NK_] = gz;
    xp[3  * (size_t)NK_] = cx;
    xp[4  * (size_t)NK_] = cy;
    xp[5  * (size_t)NK_] = cz;
    xp[6  * (size_t)NK_] = lx;
    xp[7  * (size_t)NK_] = ly;
    xp[8  * (size_t)NK_] = lz;
    xp[9  * (size_t)NK_] = f9;
    xp[10 * (size_t)NK_] = f10;
    xp[11 * (size_t)NK_] = f11;
    xp[12 * (size_t)NK_] = f12;
}

// ---------------- deterministic block reduction: 16 sums + 16 sumsqs -> 32 partials ----------------
__device__ inline void block_reduce_write(const float gsum[16], const float gsq[16], float* __restrict__ dst)
{
    __shared__ float red[4][32];
    int t = threadIdx.x, lane = t & 63, w = t >> 6;
    #pragma unroll
    for (int r = 0; r < 16; ++r) {
        float v = gsum[r];
        #pragma unroll
        for (int off = 32; off > 0; off >>= 1) v += __shfl_down(v, off);
        if (lane == 0) red[w][r] = v;
        float q = gsq[r];
        #pragma unroll
        for (int off = 32; off > 0; off >>= 1) q += __shfl_down(q, off);
        if (lane == 0) red[w][16 + r] = q;
    }
    __syncthreads();
    if (t < 32) dst[t] = red[0][t] + red[1][t] + red[2][t] + red[3][t];
}

// ---------------- stage1: conv1 -> y1g raw bf16 [b][og=8][col][8] + GN1 partial stats ----------------
__global__ __launch_bounds__(256) void stage1_kernel(const float* __restrict__ x0,
    const float* __restrict__ W1, unsigned short* __restrict__ y1g, float* __restrict__ p1)
{
    int b = blockIdx.y;
    int col = blockIdx.x * 256 + threadIdx.x;
    const float* xb = x0 + (size_t)b * 13 * NK_ + col;
    float xr[13];
    #pragma unroll
    for (int c = 0; c < 13; ++c) xr[c] = xb[(size_t)c * NK_];
    float gsum[16], gsq[16];
    #pragma unroll
    for (int r = 0; r < 16; ++r) { gsum[r] = 0.f; gsq[r] = 0.f; }
    #pragma unroll
    for (int og = 0; og < 8; ++og) {
        u16x8v row;
        #pragma unroll
        for (int oi = 0; oi < 8; ++oi) {
            int o = og * 8 + oi;
            float acc = 0.f;
            #pragma unroll
            for (int c = 0; c < 13; ++c) acc = fmaf(W1[o * 13 + c], xr[c], acc);
            row[oi] = f2us(acc);
            gsum[og * 2 + (oi >> 2)] += acc;           // GN group o>>2, compile-time index
            gsq[og * 2 + (oi >> 2)] += acc * acc;      // stats on pre-rounding fp32
        }
        *reinterpret_cast<u16x8v*>(y1g + (((size_t)b * 8 + og) * NK_ + col) * 8) = row;
    }
    block_reduce_write(gsum, gsq, p1 + ((size_t)b * NBLK_ + blockIdx.x) * 32);
}

// ---------------- fold GN into per-(b,c) scale/shift from block partials: one WAVE per (b,c) ----------------
template<int COUT>
__global__ __launch_bounds__(256) void finalize_kernel(const float* __restrict__ part,
    const float* __restrict__ gamma, const float* __restrict__ beta,
    float* __restrict__ ga, float* __restrict__ sh)
{
    int wv = blockIdx.x * 4 + (threadIdx.x >> 6);   // wave id = b*COUT + c
    int lane = threadIdx.x & 63;
    int b = wv / COUT, c = wv % COUT;
    int g = c / (COUT / G_);
    float sum = 0.f, sq = 0.f;
    for (int blk = lane; blk < NBLK_; blk += 64) {
        const float* d = part + ((size_t)b * NBLK_ + blk) * 32;
        sum += d[g]; sq += d[16 + g];
    }
    #pragma unroll
    for (int off = 32; off > 0; off >>= 1) {
        sum += __shfl_down(sum, off);
        sq  += __shfl_down(sq, off);
    }
    if (lane == 0) {
        float cnt = (float)(COUT / G_) * (float)NK_;
        float mean = sum / cnt;
        float var = fmaxf(sq / cnt - mean * mean, 0.f);
        float sc = gamma[c] * rsqrtf(var + EPS_);
        ga[wv] = sc;
        sh[wv] = beta[c] - mean * sc;
    }
}

// ---------------- finalizeM: GN fold from MFMA partials [b][1024 sets][32] (e = 2g) ----------------
template<int COUT>
__global__ __launch_bounds__(256) void finalizeM_kernel(const float* __restrict__ pm,
    const float* __restrict__ gamma, const float* __restrict__ beta,
    float* __restrict__ ga, float* __restrict__ sh)
{
    int wv = blockIdx.x * 4 + (threadIdx.x >> 6);   // wave id = b*COUT + c
    int lane = threadIdx.x & 63;
    int b = wv / COUT, c = wv % COUT;
    int g = c / (COUT / G_);
    int e = g * 2;
    float sum = 0.f, sq = 0.f;
    for (int s = lane; s < 1024; s += 64) {
        const float* d = pm + ((size_t)(b * 1024 + s)) * 32;
        sum += d[e]; sq += d[e + 1];
    }
    #pragma unroll
    for (int off = 32; off > 0; off >>= 1) {
        sum += __shfl_down(sum, off);
        sq  += __shfl_down(sq, off);
    }
    if (lane == 0) {
        float cnt = (float)(COUT / G_) * (float)NK_;
        float mean = sum / cnt;
        float var = fmaxf(sq / cnt - mean * mean, 0.f);
        float sc = gamma[c] * rsqrtf(var + EPS_);
        ga[wv] = sc;
        sh[wv] = beta[c] - mean * sc;
    }
}

// ---------------- weight -> bf16 casts ----------------
__global__ __launch_bounds__(256) void wcast_kernel(const float* __restrict__ W, bf16* __restrict__ Wb, int n)
{
    int t = blockIdx.x * 256 + threadIdx.x;
    if (t < n) Wb[t] = f2b(W[t]);
}

// ---------------- prep64: in-place x = bf16(relu(a*y + s)) on 64-ch grouped [b][cg=8][col][8c] ----------------
__global__ __launch_bounds__(256) void prep64_kernel(unsigned short* __restrict__ yg,
    const float* __restrict__ a, const float* __restrict__ s)
{
    size_t t = (size_t)blockIdx.x * 256 + threadIdx.x;   // one (b,cg,col) 16B chunk
    int b  = (int)(t / ((size_t)8 * NK_));
    int cg = (int)((t / NK_) & 7);
    const float* ab = a + b * 64 + cg * 8;
    const float* sb = s + b * 64 + cg * 8;
    u16x8v v = *reinterpret_cast<const u16x8v*>(yg + t * 8);
    #pragma unroll
    for (int j = 0; j < 8; ++j)
        v[j] = f2us(fmaxf(fmaf(us2f(v[j]), ab[j], sb[j]), 0.f));
    *reinterpret_cast<u16x8v*>(yg + t * 8) = v;
}

// ---------------- stage2 via MFMA: y2 = W2(64x64) x x1 -> y2g grouped + GN2 partials ----------------
// grid (N_/16, 1, B); 4 waves split 20 neighbors (k = kk*4 + w). Same fragment algebra as stage3.
// GN2: 4ch groups; per d-tile quarter q=lane>>4 -> group ot*4+q; width-16 reduce.
// p2m: [b][ntile*4+w][32], entry (ot*4+q)*2 + {0,1}.
__global__ __launch_bounds__(256) void stage2_mfma_kernel(
    const short* __restrict__ x1g, const short* __restrict__ w2b,
    unsigned short* __restrict__ y2g, float* __restrict__ p2m)
{
    int ntile = blockIdx.x, b = blockIdx.z;
    int lane = threadIdx.x & 63, w = threadIdx.x >> 6;
    int colbase = ntile * 16 + (lane & 15);
    int cme = (lane >> 4) * 8;

    bf16x8v afr[4][2];
    #pragma unroll
    for (int ot = 0; ot < 4; ++ot)
        #pragma unroll
        for (int kb = 0; kb < 2; ++kb)
            afr[ot][kb] = *reinterpret_cast<const bf16x8v*>(
                w2b + (size_t)(ot * 16 + (lane & 15)) * 64 + kb * 32 + cme);

    float psum[4], psq[4];
    #pragma unroll
    for (int ot = 0; ot < 4; ++ot) { psum[ot] = 0.f; psq[ot] = 0.f; }

    for (int kk = 0; kk < 5; ++kk) {
        int k = kk * 4 + w;
        int colme = k * N_ + colbase;
        bf16x8v bfr[2];
        #pragma unroll
        for (int kb = 0; kb < 2; ++kb) {
            int cg = kb * 4 + (lane >> 4);
            bfr[kb] = *reinterpret_cast<const bf16x8v*>(
                x1g + (((size_t)b * 8 + cg) * NK_ + colme) * 8);
        }
        #pragma unroll
        for (int ot = 0; ot < 4; ++ot) {
            f32x4v acc = { 0.f, 0.f, 0.f, 0.f };
            acc = __builtin_amdgcn_mfma_f32_16x16x32_bf16(afr[ot][0], bfr[0], acc, 0, 0, 0);
            acc = __builtin_amdgcn_mfma_f32_16x16x32_bf16(afr[ot][1], bfr[1], acc, 0, 0, 0);
            u16x4v sv;
            #pragma unroll
            for (int j = 0; j < 4; ++j) {
                float v = acc[j];
                sv[j] = f2us(v);
                psum[ot] += v; psq[ot] += v * v;
            }
            int cgo = ot * 2 + (lane >> 5);           // output c-group (8ch)
            *reinterpret_cast<u16x4v*>(
                y2g + (((size_t)b * 8 + cgo) * NK_ + colme) * 8 + ((lane >> 4) & 1) * 4) = sv;
        }
    }
    float* dst = p2m + ((size_t)(b * 256 + ntile) * 4 + w) * 32;
    int qq = lane >> 4;
    #pragma unroll
    for (int ot = 0; ot < 4; ++ot) {
        float s = psum[ot], q = psq[ot];
        #pragma unroll
        for (int off = 8; off > 0; off >>= 1) {
            s += __shfl_down(s, off, 16);
            q += __shfl_down(q, off, 16);
        }
        if ((lane & 15) == 0) {
            dst[(ot * 4 + qq) * 2 + 0] = s;
            dst[(ot * 4 + qq) * 2 + 1] = q;
        }
    }
}

// ---------------- stage3 via MFMA: y3 = W3(128x64) x x2 -> y3g grouped + GN3 partials ----------------
__global__ __launch_bounds__(256) void stage3_mfma_kernel(
    const short* __restrict__ x2g, const short* __restrict__ w3b,
    unsigned short* __restrict__ y3g, float* __restrict__ p3m)
{
    int ntile = blockIdx.x, b = blockIdx.z;
    int lane = threadIdx.x & 63, w = threadIdx.x >> 6;
    int colbase = ntile * 16 + (lane & 15);
    int cme = (lane >> 4) * 8;

    bf16x8v afr[8][2];
    #pragma unroll
    for (int ot = 0; ot < 8; ++ot)
        #pragma unroll
        for (int kb = 0; kb < 2; ++kb)
            afr[ot][kb] = *reinterpret_cast<const bf16x8v*>(
                w3b + (size_t)(ot * 16 + (lane & 15)) * 64 + kb * 32 + cme);

    float psum[8], psq[8];
    #pragma unroll
    for (int ot = 0; ot < 8; ++ot) { psum[ot] = 0.f; psq[ot] = 0.f; }

    for (int kk = 0; kk < 5; ++kk) {
        int k = kk * 4 + w;
        int colme = k * N_ + colbase;
        bf16x8v bfr[2];
        #pragma unroll
        for (int kb = 0; kb < 2; ++kb) {
            int cg = kb * 4 + (lane >> 4);
            bfr[kb] = *reinterpret_cast<const bf16x8v*>(
                x2g + (((size_t)b * 8 + cg) * NK_ + colme) * 8);
        }
        #pragma unroll
        for (int ot = 0; ot < 8; ++ot) {
            f32x4v acc = { 0.f, 0.f, 0.f, 0.f };
            acc = __builtin_amdgcn_mfma_f32_16x16x32_bf16(afr[ot][0], bfr[0], acc, 0, 0, 0);
            acc = __builtin_amdgcn_mfma_f32_16x16x32_bf16(afr[ot][1], bfr[1], acc, 0, 0, 0);
            u16x4v sv;
            #pragma unroll
            for (int j = 0; j < 4; ++j) {
                float v = acc[j];
                sv[j] = f2us(v);
                psum[ot] += v; psq[ot] += v * v;
            }
            int g = ot * 2 + (lane >> 5);
            *reinterpret_cast<u16x4v*>(
                y3g + (((size_t)b * 16 + g) * NK_ + colme) * 8 + ((lane >> 4) & 1) * 4) = sv;
        }
    }
    float* dst = p3m + ((size_t)(b * 256 + ntile) * 4 + w) * 32;
    #pragma unroll
    for (int ot = 0; ot < 8; ++ot) {
        float s = psum[ot], q = psq[ot];
        #pragma unroll
        for (int off = 16; off > 0; off >>= 1) {
            s += __shfl_down(s, off, 32);
            q += __shfl_down(q, off, 32);
        }
        if ((lane & 31) == 0) {
            int half = lane >> 5;
            dst[ot * 4 + half * 2 + 0] = s;
            dst[ot * 4 + half * 2 + 1] = q;
        }
    }
}

// ---------------- prep4: in-place x3 = bf16(relu(a3*y3 + s3)) on y3g [b][cg=16][col][8c] ----------------
__global__ __launch_bounds__(256) void prep4_kernel(unsigned short* __restrict__ y3g,
    const float* __restrict__ a3, const float* __restrict__ s3)
{
    size_t t = (size_t)blockIdx.x * 256 + threadIdx.x;   // one (b,cg,col) 16B chunk
    int b  = (int)(t / ((size_t)16 * NK_));
    int cg = (int)((t / NK_) & 15);
    const float* ab = a3 + b * 128 + cg * 8;
    const float* sb = s3 + b * 128 + cg * 8;
    u16x8v v = *reinterpret_cast<const u16x8v*>(y3g + t * 8);
    #pragma unroll
    for (int j = 0; j < 8; ++j)
        v[j] = f2us(fmaxf(fmaf(us2f(v[j]), ab[j], sb[j]), 0.f));
    *reinterpret_cast<u16x8v*>(y3g + t * 8) = v;
}

// ---------------- conv4 via MFMA: block = 16n tile, 4 waves x 4 o-passes = all 256 o ----------------
__global__ __launch_bounds__(256) void conv4_mfma_kernel(
    const short* __restrict__ x3g, const short* __restrict__ w4b,
    float* __restrict__ m4, float* __restrict__ part)
{
    int ntile = blockIdx.x, b = blockIdx.z;
    int lane = threadIdx.x & 63, w = threadIdx.x >> 6;
    int colme = ntile * 16 + (lane & 15);
    int cme = (lane >> 4) * 8;

    bf16x8v afr[4][4];
    #pragma unroll
    for (int p = 0; p < 4; ++p) {
        #pragma unroll
        for (int cb = 0; cb < 4; ++cb) {
            size_t aoff = (size_t)(p * 64 + w * 16 + (lane & 15)) * 128 + cb * 32 + cme;
            afr[p][cb] = *reinterpret_cast<const bf16x8v*>(w4b + aoff);
        }
    }

    float am[4][4];
    #pragma unroll
    for (int p = 0; p < 4; ++p)
        #pragma unroll
        for (int j = 0; j < 4; ++j) am[p][j] = -INFINITY;
    float ps[4] = {0.f, 0.f, 0.f, 0.f}, pq[4] = {0.f, 0.f, 0.f, 0.f};

    for (int k = 0; k < K_; ++k) {
        bf16x8v bfr[4];
        #pragma unroll
        for (int cb = 0; cb < 4; ++cb) {
            int cg = cb * 4 + (lane >> 4);
            bfr[cb] = *reinterpret_cast<const bf16x8v*>(
                x3g + (((size_t)b * 16 + cg) * NK_ + (size_t)k * N_ + colme) * 8);
        }
        #pragma unroll
        for (int p = 0; p < 4; ++p) {
            f32x4v acc = { 0.f, 0.f, 0.f, 0.f };
            #pragma unroll
            for (int cb = 0; cb < 4; ++cb)
                acc = __builtin_amdgcn_mfma_f32_16x16x32_bf16(afr[p][cb], bfr[cb], acc, 0, 0, 0);
            #pragma unroll
            for (int j = 0; j < 4; ++j) {
                float v = acc[j];
                am[p][j] = fmaxf(am[p][j], v);
                ps[p] += v; pq[p] += v * v;
            }
        }
    }
    #pragma unroll
    for (int p = 0; p < 4; ++p) {
        #pragma unroll
        for (int j = 0; j < 4; ++j) {
            int o = p * 64 + w * 16 + (lane >> 4) * 4 + j;
            m4[((size_t)b * 256 + o) * N_ + colme] = am[p][j];
        }
        float s = ps[p], q = pq[p];
        #pragma unroll
        for (int off = 32; off > 0; off >>= 1) {
            s += __shfl_down(s, off);
            q += __shfl_down(q, off);
        }
        if (lane == 0) {
            int g = p * 4 + w;
            part[((b * 16 + g) * 2 + 0) * 256 + ntile] = s;
            part[((b * 16 + g) * 2 + 1) * 256 + ntile] = q;
        }
    }
}

// ---------------- GN4 finalize: one WAVE per (b,c), coalesced 256-entry rows ----------------
__global__ __launch_bounds__(256) void finalize4_kernel(const float* __restrict__ part,
    const float* __restrict__ gamma, const float* __restrict__ beta,
    float* __restrict__ ga, float* __restrict__ sh)
{
    int wv = blockIdx.x * 4 + (threadIdx.x >> 6);   // 0..1023 = b*256 + c
    int lane = threadIdx.x & 63;
    int b = wv >> 8, c = wv & 255;
    int g = c >> 4;
    float sum = 0.f, sq = 0.f;
    for (int nt = lane; nt < 256; nt += 64) {
        sum += part[((b * 16 + g) * 2 + 0) * 256 + nt];
        sq  += part[((b * 16 + g) * 2 + 1) * 256 + nt];
    }
    #pragma unroll
    for (int off = 32; off > 0; off >>= 1) {
        sum += __shfl_down(sum, off);
        sq  += __shfl_down(sq, off);
    }
    if (lane == 0) {
        float cnt = 16.f * (float)NK_;
        float mean = sum / cnt;
        float var = fmaxf(sq / cnt - mean * mean, 0.f);
        float sc = gamma[c] * rsqrtf(var + EPS_);
        ga[wv] = sc;
        sh[wv] = beta[c] - mean * sc;
    }
}

// ---------------- final: out = relu(a*max_k + s)  (valid since a>0) ----------------
__global__ __launch_bounds__(256) void apply_kernel(const float* __restrict__ m4,
    const float* __restrict__ ga, const float* __restrict__ sh, float* __restrict__ out)
{
    int t = blockIdx.x * 256 + threadIdx.x;   // b*256*N + c*N + n
    int bc = t >> 12;
    out[t] = fmaxf(fmaf(m4[t], ga[bc], sh[bc]), 0.f);
}

extern "C" void kernel_launch(void* const* d_in, const int* in_sizes, int n_in,
                              void* d_out, int out_size, void* d_ws, size_t ws_size,
                              hipStream_t stream)
{
    const float* pts = (const float*)d_in[0];
    const float* W1 = (const float*)d_in[1];
    const float* g1 = (const float*)d_in[2];
    const float* bt1 = (const float*)d_in[3];
    const float* W2 = (const float*)d_in[4];
    const float* g2 = (const float*)d_in[5];
    const float* bt2 = (const float*)d_in[6];
    const float* W3 = (const float*)d_in[7];
    const float* g3 = (const float*)d_in[8];
    const float* bt3 = (const float*)d_in[9];
    const float* W4 = (const float*)d_in[10];
    const float* g4 = (const float*)d_in[11];
    const float* bt4 = (const float*)d_in[12];
    float* out = (float*)d_out;

    char* ws = (char*)d_ws;
    size_t off = 0;
    auto alloc = [&](size_t bytes) -> void* {
        void* p = ws + off;
        off = (off + bytes + 255) & ~(size_t)255;
        return p;
    };
    int*   idx  = (int*)  alloc((size_t)B_ * NK_ * 4);           // 1.3 MB
    float* x0   = (float*)alloc((size_t)B_ * 13 * NK_ * 4);      // 17 MB
    unsigned short* y2g = (unsigned short*)alloc((size_t)B_ * 8 * NK_ * 8 * 2);   // 42 MB
    unsigned short* y3g = (unsigned short*)alloc((size_t)B_ * 16 * NK_ * 8 * 2);  // 84 MB
    unsigned short* y1g = y3g;   // ALIAS: y1g (42 MB) lives in y3g's buffer; dead before stage3 writes
    float* m4   = (float*)alloc((size_t)B_ * 256 * N_ * 4);      // 16.8 MB
    bf16*  w2b  = (bf16*) alloc(64 * 64 * 2);                    // 8 KB
    bf16*  w3b  = (bf16*) alloc(128 * 64 * 2);                   // 16 KB
    bf16*  w4b  = (bf16*) alloc(256 * 128 * 2);                  // 64 KB
    float* p1   = (float*)alloc((size_t)B_ * NBLK_ * 32 * 4);    // 164 KB
    float* p2m  = (float*)alloc((size_t)B_ * 1024 * 32 * 4);     // 0.5 MB
    float* p3m  = (float*)alloc((size_t)B_ * 1024 * 32 * 4);     // 0.5 MB
    float* part4= (float*)alloc(4 * 16 * 2 * 256 * 4);           // 128 KB
    float* a1 = (float*)alloc(B_ * 64 * 4);
    float* s1 = (float*)alloc(B_ * 64 * 4);
    float* a2 = (float*)alloc(B_ * 64 * 4);
    float* s2 = (float*)alloc(B_ * 64 * 4);
    float* a3 = (float*)alloc(B_ * 128 * 4);
    float* s3 = (float*)alloc(B_ * 128 * 4);
    float* a4 = (float*)alloc(B_ * 256 * 4);
    float* s4 = (float*)alloc(B_ * 256 * 4);
    (void)ws_size; (void)in_sizes; (void)n_in; (void)out_size;

    knn_kernel<<<(B_ * N_) / 4, 256, 0, stream>>>(pts, idx);
    wcast_kernel<<<16, 256, 0, stream>>>(W2, w2b, 64 * 64);
    wcast_kernel<<<32, 256, 0, stream>>>(W3, w3b, 128 * 64);
    wcast_kernel<<<128, 256, 0, stream>>>(W4, w4b, 256 * 128);
    feature_kernel<<<(B_ * NK_) / 256, 256, 0, stream>>>(pts, idx, x0);

    stage1_kernel<<<dim3(NBLK_, B_), 256, 0, stream>>>(x0, W1, y1g, p1);
    finalize_kernel<64><<<64, 256, 0, stream>>>(p1, g1, bt1, a1, s1);

    prep64_kernel<<<(int)(((size_t)B_ * 8 * NK_) / 256), 256, 0, stream>>>(y1g, a1, s1);
    stage2_mfma_kernel<<<dim3(N_ / 16, 1, B_), 256, 0, stream>>>((const short*)y1g, (const short*)w2b, y2g, p2m);
    finalizeM_kernel<64><<<64, 256, 0, stream>>>(p2m, g2, bt2, a2, s2);

    prep64_kernel<<<(int)(((size_t)B_ * 8 * NK_) / 256), 256, 0, stream>>>(y2g, a2, s2);
    stage3_mfma_kernel<<<dim3(N_ / 16, 1, B_), 256, 0, stream>>>((const short*)y2g, (const short*)w3b, y3g, p3m);
    finalizeM_kernel<128><<<128, 256, 0, stream>>>(p3m, g3, bt3, a3, s3);

    prep4_kernel<<<(int)(((size_t)B_ * 16 * NK_) / 256), 256, 0, stream>>>(y3g, a3, s3);
    conv4_mfma_kernel<<<dim3(N_ / 16, 1, B_), 256, 0, stream>>>((const short*)y3g, (const short*)w4b, m4, part4);
    finalize4_kernel<<<256, 256, 0, stream>>>(part4, g4, bt4, a4, s4);

    apply_kernel<<<(B_ * 256 * N_) / 256, 256, 0, stream>>>(m4, a4, s4, out);
}

// Round 21
// 346.950 us; speedup vs baseline: 1.9942x; 1.0821x over previous
//
#include <hip/hip_runtime.h>
#include <hip/hip_bf16.h>
#include <math.h>

#define B_ 4
#define N_ 4096
#define K_ 20
#define NK_ (N_*K_)   // 81920
#define G_ 16
#define EPS_ 1e-5f
#define NBLK_ (NK_/256)   // 320 column-blocks per batch

typedef __hip_bfloat16 bf16;
typedef short bf16x8v __attribute__((ext_vector_type(8)));
typedef unsigned short u16x8v __attribute__((ext_vector_type(8)));
typedef unsigned short u16x4v __attribute__((ext_vector_type(4)));
typedef float f32x4v __attribute__((ext_vector_type(4)));

__device__ inline float b2f(bf16 v) { return __bfloat162float(v); }
__device__ inline bf16  f2b(float v){ return __float2bfloat16(v); }
__device__ inline float us2f(unsigned short u){ unsigned int i = ((unsigned)u) << 16; float f; __builtin_memcpy(&f, &i, 4); return f; }
__device__ inline unsigned short f2us(float f){ bf16 h = __float2bfloat16(f); unsigned short u; __builtin_memcpy(&u, &h, 2); return u; }

// DPP move with -INF fill for disabled/out-of-row lanes (VALU-speed cross-lane)
__device__ inline float dppmovf(float v, int ctrl_unused, const int CTRL)
{
    return v; // placeholder (not used)
}
template<int CTRL>
__device__ inline float dppmax_step(float v)
{
    int i; __builtin_memcpy(&i, &v, 4);
    int m = __builtin_amdgcn_update_dpp((int)0xFF800000, i, CTRL, 0xF, 0xF, false);
    float f; __builtin_memcpy(&f, &m, 4);
    return fmaxf(v, f);
}

// ---------------- kNN: one WAVE per (b,i); two-level cache + DPP wave-max ----------------
// pd arithmetic bit-exact np (no FMA, sequential adds) — LOAD-BEARING, do not change.
// Selection semantics identical to r19/r20 (ties proven absent in this data).
__global__ __launch_bounds__(256) void knn_kernel(const float* __restrict__ pts, int* __restrict__ idx)
{
    int wid  = (blockIdx.x << 2) | (threadIdx.x >> 6);   // global wave id = b*N + i
    int lane = threadIdx.x & 63;
    int b = wid >> 12, i = wid & (N_ - 1);
    const float* pb = pts + (size_t)b * 6 * N_;
    float xi = pb[i], yi = pb[N_ + i], zi = pb[2 * N_ + i];
    float xxi = __fadd_rn(__fadd_rn(__fmul_rn(xi, xi), __fmul_rn(yi, yi)), __fmul_rn(zi, zi));
    float nxxi = -xxi;

    float pd[64];                    // candidate j = c*64 + lane (statically indexed only)
    #pragma unroll
    for (int c = 0; c < 64; ++c) {
        int j = c * 64 + lane;
        float xj = pb[j], yj = pb[N_ + j], zj = pb[2 * N_ + j];
        float xxj = __fadd_rn(__fadd_rn(__fmul_rn(xj, xj), __fmul_rn(yj, yj)), __fmul_rn(zj, zj));
        float px = __fmul_rn(xi, xj);
        float py = __fmul_rn(yi, yj);
        float pz = __fmul_rn(zi, zj);
        float dot = __fadd_rn(__fadd_rn(px, py), pz);   // NO FMA — matches np
        float inner = __fmul_rn(-2.0f, dot);
        pd[c] = __fsub_rn(__fsub_rn(nxxi, inner), xxj);
    }

    // rank 0 = self: pd[i,i] = +0 exactly is the strict max; emit and retire
    {
        int slot = __builtin_amdgcn_readfirstlane(i >> 6);
        int ln   = __builtin_amdgcn_readfirstlane(i & 63);
        bool me = (lane == ln);
        #pragma unroll
        for (int c = 0; c < 64; ++c)
            if (c == slot) pd[c] = me ? -INFINITY : pd[c];
        if (lane == 0) idx[(size_t)b * NK_ + i] = i;
    }

    float gmax[8];
    #pragma unroll
    for (int g = 0; g < 8; ++g) {
        float m01 = fmaxf(pd[g * 8 + 0], pd[g * 8 + 1]);
        float m23 = fmaxf(pd[g * 8 + 2], pd[g * 8 + 3]);
        float m45 = fmaxf(pd[g * 8 + 4], pd[g * 8 + 5]);
        float m67 = fmaxf(pd[g * 8 + 6], pd[g * 8 + 7]);
        gmax[g] = fmaxf(fmaxf(m01, m23), fmaxf(m45, m67));
    }

    for (int it = 1; it < K_; ++it) {
        // lane max over 8 cached group maxima (7 ops, log depth)
        float a01 = fmaxf(gmax[0], gmax[1]);
        float a23 = fmaxf(gmax[2], gmax[3]);
        float a45 = fmaxf(gmax[4], gmax[5]);
        float a67 = fmaxf(gmax[6], gmax[7]);
        float vb = fmaxf(fmaxf(a01, a23), fmaxf(a45, a67));

        // wave max via DPP cascade (all VALU; lane 63 ends with global max)
        float r = vb;
        r = dppmax_step<0x111>(r);   // row_shr:1
        r = dppmax_step<0x112>(r);   // row_shr:2
        r = dppmax_step<0x114>(r);   // row_shr:4
        r = dppmax_step<0x118>(r);   // row_shr:8
        r = dppmax_step<0x142>(r);   // row_bcast15
        r = dppmax_step<0x143>(r);   // row_bcast31
        int wvi = __builtin_amdgcn_readlane(__float_as_int(r), 63);
        float wv = __int_as_float(wvi);                 // wave-uniform max value

        unsigned long long mk = __ballot(vb == wv);
        int wl = 63 - __builtin_clzll(mk);              // winner lane (uniform)

        int gsel = 0;
        #pragma unroll
        for (int g = 0; g < 8; ++g)
            if (gmax[g] == wv) gsel = g;
        int gw = __builtin_amdgcn_readlane(gsel, wl);   // v_readlane: 1 VALU op

        int usel = 0;
        #pragma unroll
        for (int g = 0; g < 8; ++g)
            if (g == gw) {                               // gw uniform -> static branch
                #pragma unroll
                for (int u = 0; u < 8; ++u)
                    if (pd[g * 8 + u] == wv) usel = u;
            }
        int uw = __builtin_amdgcn_readlane(usel, wl);

        int bj = (gw * 8 + uw) * 64 + wl;
        if (lane == 0) idx[(size_t)b * NK_ + it * N_ + i] = bj;

        // retire winner slot + recompute only that group's max (static on gw,uw)
        bool me = (lane == wl);
        #pragma unroll
        for (int g = 0; g < 8; ++g)
            if (g == gw) {
                #pragma unroll
                for (int u = 0; u < 8; ++u)
                    if (u == uw) pd[g * 8 + u] = me ? -INFINITY : pd[g * 8 + u];
                float m01 = fmaxf(pd[g * 8 + 0], pd[g * 8 + 1]);
                float m23 = fmaxf(pd[g * 8 + 2], pd[g * 8 + 3]);
                float m45 = fmaxf(pd[g * 8 + 4], pd[g * 8 + 5]);
                float m67 = fmaxf(pd[g * 8 + 6], pd[g * 8 + 7]);
                gmax[g] = fmaxf(fmaxf(m01, m23), fmaxf(m45, m67));
            }
    }
}

// ---------------- angle: "x<0" quadrant predicate — LOAD-BEARING (round 10) ----------------
__device__ inline float angle3(float ax, float ay, float az, float bx, float by, float bz)
{
    float cx = __fsub_rn(__fmul_rn(ay, bz), __fmul_rn(az, by));
    float cy = __fsub_rn(__fmul_rn(az, bx), __fmul_rn(ax, bz));
    float cz = __fsub_rn(__fmul_rn(ax, by), __fmul_rn(ay, bx));
    float cn = sqrtf(__fadd_rn(__fadd_rn(__fmul_rn(cx, cx), __fmul_rn(cy, cy)), __fmul_rn(cz, cz)));
    float d  = __fadd_rn(__fadd_rn(__fmul_rn(ax, bx), __fmul_rn(ay, by)), __fmul_rn(az, bz));
    if (cn == 0.0f)
        return (d < 0.0f) ? 3.14159274101257324e+00f : 0.0f;   // -0 -> 0
    return atan2f(cn, d);
}

__global__ __launch_bounds__(256) void feature_kernel(const float* __restrict__ pts,
                                                      const int* __restrict__ idx,
                                                      float* __restrict__ x0)
{
    int t = blockIdx.x * 256 + threadIdx.x;           // [0, B*NK)
    int col = t % NK_;
    int b = t / NK_;
    int n = col & (N_ - 1);
    int j = idx[t];
    const float* pb = pts + (size_t)b * 6 * N_;
    float cx = pb[n],            cy = pb[N_ + n],     cz = pb[2 * N_ + n];
    float gx = pb[j],            gy = pb[N_ + j],     gz = pb[2 * N_ + j];
    float rx = pb[3 * N_ + n],   ry = pb[4 * N_ + n], rz = pb[5 * N_ + n];
    float ix = pb[3 * N_ + j],   iy = pb[4 * N_ + j], iz = pb[5 * N_ + j];
    float lx = __fsub_rn(gx, cx), ly = __fsub_rn(gy, cy), lz = __fsub_rn(gz, cz);

    float f9  = angle3(rx, ry, rz, lx, ly, lz);
    float f10 = angle3(ix, iy, iz, lx, ly, lz);
    float f11 = angle3(rx, ry, rz, ix, iy, iz);
    float f12 = sqrtf(__fadd_rn(__fadd_rn(__fmul_rn(lx, lx), __fmul_rn(ly, ly)), __fmul_rn(lz, lz)));

    float* xp = x0 + (size_t)b * 13 * NK_ + col;
    xp[0  * (size_t)NK_] = gx;
    xp[1  * (size_t)NK_] = gy;
    xp[2  * (size_t)NK_] = gz;
    xp[3  * (size_t)NK_] = cx;
    xp[4  * (size_t)NK_] = cy;
    xp[5  * (size_t)NK_] = cz;
    xp[6  * (size_t)NK_] = lx;
    xp[7  * (size_t)NK_] = ly;
    xp[8  * (size_t)NK_] = lz;
    xp[9  * (size_t)NK_] = f9;
    xp[10 * (size_t)NK_] = f10;
    xp[11 * (size_t)NK_] = f11;
    xp[12 * (size_t)NK_] = f12;
}

// ---------------- deterministic block reduction: 16 sums + 16 sumsqs -> 32 partials ----------------
__device__ inline void block_reduce_write(const float gsum[16], const float gsq[16], float* __restrict__ dst)
{
    __shared__ float red[4][32];
    int t = threadIdx.x, lane = t & 63, w = t >> 6;
    #pragma unroll
    for (int r = 0; r < 16; ++r) {
        float v = gsum[r];
        #pragma unroll
        for (int off = 32; off > 0; off >>= 1) v += __shfl_down(v, off);
        if (lane == 0) red[w][r] = v;
        float q = gsq[r];
        #pragma unroll
        for (int off = 32; off > 0; off >>= 1) q += __shfl_down(q, off);
        if (lane == 0) red[w][16 + r] = q;
    }
    __syncthreads();
    if (t < 32) dst[t] = red[0][t] + red[1][t] + red[2][t] + red[3][t];
}

// ---------------- stage1: conv1 -> y1g raw bf16 [b][og=8][col][8] + GN1 partial stats ----------------
__global__ __launch_bounds__(256) void stage1_kernel(const float* __restrict__ x0,
    const float* __restrict__ W1, unsigned short* __restrict__ y1g, float* __restrict__ p1)
{
    int b = blockIdx.y;
    int col = blockIdx.x * 256 + threadIdx.x;
    const float* xb = x0 + (size_t)b * 13 * NK_ + col;
    float xr[13];
    #pragma unroll
    for (int c = 0; c < 13; ++c) xr[c] = xb[(size_t)c * NK_];
    float gsum[16], gsq[16];
    #pragma unroll
    for (int r = 0; r < 16; ++r) { gsum[r] = 0.f; gsq[r] = 0.f; }
    #pragma unroll
    for (int og = 0; og < 8; ++og) {
        u16x8v row;
        #pragma unroll
        for (int oi = 0; oi < 8; ++oi) {
            int o = og * 8 + oi;
            float acc = 0.f;
            #pragma unroll
            for (int c = 0; c < 13; ++c) acc = fmaf(W1[o * 13 + c], xr[c], acc);
            row[oi] = f2us(acc);
            gsum[og * 2 + (oi >> 2)] += acc;           // GN group o>>2, compile-time index
            gsq[og * 2 + (oi >> 2)] += acc * acc;      // stats on pre-rounding fp32
        }
        *reinterpret_cast<u16x8v*>(y1g + (((size_t)b * 8 + og) * NK_ + col) * 8) = row;
    }
    block_reduce_write(gsum, gsq, p1 + ((size_t)b * NBLK_ + blockIdx.x) * 32);
}

// ---------------- fold GN into per-(b,c) scale/shift from block partials: one WAVE per (b,c) ----------------
template<int COUT>
__global__ __launch_bounds__(256) void finalize_kernel(const float* __restrict__ part,
    const float* __restrict__ gamma, const float* __restrict__ beta,
    float* __restrict__ ga, float* __restrict__ sh)
{
    int wv = blockIdx.x * 4 + (threadIdx.x >> 6);   // wave id = b*COUT + c
    int lane = threadIdx.x & 63;
    int b = wv / COUT, c = wv % COUT;
    int g = c / (COUT / G_);
    float sum = 0.f, sq = 0.f;
    for (int blk = lane; blk < NBLK_; blk += 64) {
        const float* d = part + ((size_t)b * NBLK_ + blk) * 32;
        sum += d[g]; sq += d[16 + g];
    }
    #pragma unroll
    for (int off = 32; off > 0; off >>= 1) {
        sum += __shfl_down(sum, off);
        sq  += __shfl_down(sq, off);
    }
    if (lane == 0) {
        float cnt = (float)(COUT / G_) * (float)NK_;
        float mean = sum / cnt;
        float var = fmaxf(sq / cnt - mean * mean, 0.f);
        float sc = gamma[c] * rsqrtf(var + EPS_);
        ga[wv] = sc;
        sh[wv] = beta[c] - mean * sc;
    }
}

// ---------------- finalizeM: GN fold from MFMA partials [b][1024 sets][32] (e = 2g) ----------------
template<int COUT>
__global__ __launch_bounds__(256) void finalizeM_kernel(const float* __restrict__ pm,
    const float* __restrict__ gamma, const float* __restrict__ beta,
    float* __restrict__ ga, float* __restrict__ sh)
{
    int wv = blockIdx.x * 4 + (threadIdx.x >> 6);   // wave id = b*COUT + c
    int lane = threadIdx.x & 63;
    int b = wv / COUT, c = wv % COUT;
    int g = c / (COUT / G_);
    int e = g * 2;
    float sum = 0.f, sq = 0.f;
    for (int s = lane; s < 1024; s += 64) {
        const float* d = pm + ((size_t)(b * 1024 + s)) * 32;
        sum += d[e]; sq += d[e + 1];
    }
    #pragma unroll
    for (int off = 32; off > 0; off >>= 1) {
        sum += __shfl_down(sum, off);
        sq  += __shfl_down(sq, off);
    }
    if (lane == 0) {
        float cnt = (float)(COUT / G_) * (float)NK_;
        float mean = sum / cnt;
        float var = fmaxf(sq / cnt - mean * mean, 0.f);
        float sc = gamma[c] * rsqrtf(var + EPS_);
        ga[wv] = sc;
        sh[wv] = beta[c] - mean * sc;
    }
}

// ---------------- weight -> bf16 casts ----------------
__global__ __launch_bounds__(256) void wcast_kernel(const float* __restrict__ W, bf16* __restrict__ Wb, int n)
{
    int t = blockIdx.x * 256 + threadIdx.x;
    if (t < n) Wb[t] = f2b(W[t]);
}

// ---------------- prep64: in-place x = bf16(relu(a*y + s)) on 64-ch grouped [b][cg=8][col][8c] ----------------
__global__ __launch_bounds__(256) void prep64_kernel(unsigned short* __restrict__ yg,
    const float* __restrict__ a, const float* __restrict__ s)
{
    size_t t = (size_t)blockIdx.x * 256 + threadIdx.x;   // one (b,cg,col) 16B chunk
    int b  = (int)(t / ((size_t)8 * NK_));
    int cg = (int)((t / NK_) & 7);
    const float* ab = a + b * 64 + cg * 8;
    const float* sb = s + b * 64 + cg * 8;
    u16x8v v = *reinterpret_cast<const u16x8v*>(yg + t * 8);
    #pragma unroll
    for (int j = 0; j < 8; ++j)
        v[j] = f2us(fmaxf(fmaf(us2f(v[j]), ab[j], sb[j]), 0.f));
    *reinterpret_cast<u16x8v*>(yg + t * 8) = v;
}

// ---------------- stage2 via MFMA: y2 = W2(64x64) x x1 -> y2g grouped + GN2 partials ----------------
__global__ __launch_bounds__(256) void stage2_mfma_kernel(
    const short* __restrict__ x1g, const short* __restrict__ w2b,
    unsigned short* __restrict__ y2g, float* __restrict__ p2m)
{
    int ntile = blockIdx.x, b = blockIdx.z;
    int lane = threadIdx.x & 63, w = threadIdx.x >> 6;
    int colbase = ntile * 16 + (lane & 15);
    int cme = (lane >> 4) * 8;

    bf16x8v afr[4][2];
    #pragma unroll
    for (int ot = 0; ot < 4; ++ot)
        #pragma unroll
        for (int kb = 0; kb < 2; ++kb)
            afr[ot][kb] = *reinterpret_cast<const bf16x8v*>(
                w2b + (size_t)(ot * 16 + (lane & 15)) * 64 + kb * 32 + cme);

    float psum[4], psq[4];
    #pragma unroll
    for (int ot = 0; ot < 4; ++ot) { psum[ot] = 0.f; psq[ot] = 0.f; }

    for (int kk = 0; kk < 5; ++kk) {
        int k = kk * 4 + w;
        int colme = k * N_ + colbase;
        bf16x8v bfr[2];
        #pragma unroll
        for (int kb = 0; kb < 2; ++kb) {
            int cg = kb * 4 + (lane >> 4);
            bfr[kb] = *reinterpret_cast<const bf16x8v*>(
                x1g + (((size_t)b * 8 + cg) * NK_ + colme) * 8);
        }
        #pragma unroll
        for (int ot = 0; ot < 4; ++ot) {
            f32x4v acc = { 0.f, 0.f, 0.f, 0.f };
            acc = __builtin_amdgcn_mfma_f32_16x16x32_bf16(afr[ot][0], bfr[0], acc, 0, 0, 0);
            acc = __builtin_amdgcn_mfma_f32_16x16x32_bf16(afr[ot][1], bfr[1], acc, 0, 0, 0);
            u16x4v sv;
            #pragma unroll
            for (int j = 0; j < 4; ++j) {
                float v = acc[j];
                sv[j] = f2us(v);
                psum[ot] += v; psq[ot] += v * v;
            }
            int cgo = ot * 2 + (lane >> 5);           // output c-group (8ch)
            *reinterpret_cast<u16x4v*>(
                y2g + (((size_t)b * 8 + cgo) * NK_ + colme) * 8 + ((lane >> 4) & 1) * 4) = sv;
        }
    }
    float* dst = p2m + ((size_t)(b * 256 + ntile) * 4 + w) * 32;
    int qq = lane >> 4;
    #pragma unroll
    for (int ot = 0; ot < 4; ++ot) {
        float s = psum[ot], q = psq[ot];
        #pragma unroll
        for (int off = 8; off > 0; off >>= 1) {
            s += __shfl_down(s, off, 16);
            q += __shfl_down(q, off, 16);
        }
        if ((lane & 15) == 0) {
            dst[(ot * 4 + qq) * 2 + 0] = s;
            dst[(ot * 4 + qq) * 2 + 1] = q;
        }
    }
}

// ---------------- stage3 via MFMA: y3 = W3(128x64) x x2 -> y3g grouped + GN3 partials ----------------
__global__ __launch_bounds__(256) void stage3_mfma_kernel(
    const short* __restrict__ x2g, const short* __restrict__ w3b,
    unsigned short* __restrict__ y3g, float* __restrict__ p3m)
{
    int ntile = blockIdx.x, b = blockIdx.z;
    int lane = threadIdx.x & 63, w = threadIdx.x >> 6;
    int colbase = ntile * 16 + (lane & 15);
    int cme = (lane >> 4) * 8;

    bf16x8v afr[8][2];
    #pragma unroll
    for (int ot = 0; ot < 8; ++ot)
        #pragma unroll
        for (int kb = 0; kb < 2; ++kb)
            afr[ot][kb] = *reinterpret_cast<const bf16x8v*>(
                w3b + (size_t)(ot * 16 + (lane & 15)) * 64 + kb * 32 + cme);

    float psum[8], psq[8];
    #pragma unroll
    for (int ot = 0; ot < 8; ++ot) { psum[ot] = 0.f; psq[ot] = 0.f; }

    for (int kk = 0; kk < 5; ++kk) {
        int k = kk * 4 + w;
        int colme = k * N_ + colbase;
        bf16x8v bfr[2];
        #pragma unroll
        for (int kb = 0; kb < 2; ++kb) {
            int cg = kb * 4 + (lane >> 4);
            bfr[kb] = *reinterpret_cast<const bf16x8v*>(
                x2g + (((size_t)b * 8 + cg) * NK_ + colme) * 8);
        }
        #pragma unroll
        for (int ot = 0; ot < 8; ++ot) {
            f32x4v acc = { 0.f, 0.f, 0.f, 0.f };
            acc = __builtin_amdgcn_mfma_f32_16x16x32_bf16(afr[ot][0], bfr[0], acc, 0, 0, 0);
            acc = __builtin_amdgcn_mfma_f32_16x16x32_bf16(afr[ot][1], bfr[1], acc, 0, 0, 0);
            u16x4v sv;
            #pragma unroll
            for (int j = 0; j < 4; ++j) {
                float v = acc[j];
                sv[j] = f2us(v);
                psum[ot] += v; psq[ot] += v * v;
            }
            int g = ot * 2 + (lane >> 5);
            *reinterpret_cast<u16x4v*>(
                y3g + (((size_t)b * 16 + g) * NK_ + colme) * 8 + ((lane >> 4) & 1) * 4) = sv;
        }
    }
    float* dst = p3m + ((size_t)(b * 256 + ntile) * 4 + w) * 32;
    #pragma unroll
    for (int ot = 0; ot < 8; ++ot) {
        float s = psum[ot], q = psq[ot];
        #pragma unroll
        for (int off = 16; off > 0; off >>= 1) {
            s += __shfl_down(s, off, 32);
            q += __shfl_down(q, off, 32);
        }
        if ((lane & 31) == 0) {
            int half = lane >> 5;
            dst[ot * 4 + half * 2 + 0] = s;
            dst[ot * 4 + half * 2 + 1] = q;
        }
    }
}

// ---------------- prep4: in-place x3 = bf16(relu(a3*y3 + s3)) on y3g [b][cg=16][col][8c] ----------------
__global__ __launch_bounds__(256) void prep4_kernel(unsigned short* __restrict__ y3g,
    const float* __restrict__ a3, const float* __restrict__ s3)
{
    size_t t = (size_t)blockIdx.x * 256 + threadIdx.x;   // one (b,cg,col) 16B chunk
    int b  = (int)(t / ((size_t)16 * NK_));
    int cg = (int)((t / NK_) & 15);
    const float* ab = a3 + b * 128 + cg * 8;
    const float* sb = s3 + b * 128 + cg * 8;
    u16x8v v = *reinterpret_cast<const u16x8v*>(y3g + t * 8);
    #pragma unroll
    for (int j = 0; j < 8; ++j)
        v[j] = f2us(fmaxf(fmaf(us2f(v[j]), ab[j], sb[j]), 0.f));
    *reinterpret_cast<u16x8v*>(y3g + t * 8) = v;
}

// ---------------- conv4 via MFMA: block = 16n tile, 4 waves x 4 o-passes = all 256 o ----------------
__global__ __launch_bounds__(256) void conv4_mfma_kernel(
    const short* __restrict__ x3g, const short* __restrict__ w4b,
    float* __restrict__ m4, float* __restrict__ part)
{
    int ntile = blockIdx.x, b = blockIdx.z;
    int lane = threadIdx.x & 63, w = threadIdx.x >> 6;
    int colme = ntile * 16 + (lane & 15);
    int cme = (lane >> 4) * 8;

    bf16x8v afr[4][4];
    #pragma unroll
    for (int p = 0; p < 4; ++p) {
        #pragma unroll
        for (int cb = 0; cb < 4; ++cb) {
            size_t aoff = (size_t)(p * 64 + w * 16 + (lane & 15)) * 128 + cb * 32 + cme;
            afr[p][cb] = *reinterpret_cast<const bf16x8v*>(w4b + aoff);
        }
    }

    float am[4][4];
    #pragma unroll
    for (int p = 0; p < 4; ++p)
        #pragma unroll
        for (int j = 0; j < 4; ++j) am[p][j] = -INFINITY;
    float ps[4] = {0.f, 0.f, 0.f, 0.f}, pq[4] = {0.f, 0.f, 0.f, 0.f};

    for (int k = 0; k < K_; ++k) {
        bf16x8v bfr[4];
        #pragma unroll
        for (int cb = 0; cb < 4; ++cb) {
            int cg = cb * 4 + (lane >> 4);
            bfr[cb] = *reinterpret_cast<const bf16x8v*>(
                x3g + (((size_t)b * 16 + cg) * NK_ + (size_t)k * N_ + colme) * 8);
        }
        #pragma unroll
        for (int p = 0; p < 4; ++p) {
            f32x4v acc = { 0.f, 0.f, 0.f, 0.f };
            #pragma unroll
            for (int cb = 0; cb < 4; ++cb)
                acc = __builtin_amdgcn_mfma_f32_16x16x32_bf16(afr[p][cb], bfr[cb], acc, 0, 0, 0);
            #pragma unroll
            for (int j = 0; j < 4; ++j) {
                float v = acc[j];
                am[p][j] = fmaxf(am[p][j], v);
                ps[p] += v; pq[p] += v * v;
            }
        }
    }
    #pragma unroll
    for (int p = 0; p < 4; ++p) {
        #pragma unroll
        for (int j = 0; j < 4; ++j) {
            int o = p * 64 + w * 16 + (lane >> 4) * 4 + j;
            m4[((size_t)b * 256 + o) * N_ + colme] = am[p][j];
        }
        float s = ps[p], q = pq[p];
        #pragma unroll
        for (int off = 32; off > 0; off >>= 1) {
            s += __shfl_down(s, off);
            q += __shfl_down(q, off);
        }
        if (lane == 0) {
            int g = p * 4 + w;
            part[((b * 16 + g) * 2 + 0) * 256 + ntile] = s;
            part[((b * 16 + g) * 2 + 1) * 256 + ntile] = q;
        }
    }
}

// ---------------- GN4 finalize: one WAVE per (b,c), coalesced 256-entry rows ----------------
__global__ __launch_bounds__(256) void finalize4_kernel(const float* __restrict__ part,
    const float* __restrict__ gamma, const float* __restrict__ beta,
    float* __restrict__ ga, float* __restrict__ sh)
{
    int wv = blockIdx.x * 4 + (threadIdx.x >> 6);   // 0..1023 = b*256 + c
    int lane = threadIdx.x & 63;
    int b = wv >> 8, c = wv & 255;
    int g = c >> 4;
    float sum = 0.f, sq = 0.f;
    for (int nt = lane; nt < 256; nt += 64) {
        sum += part[((b * 16 + g) * 2 + 0) * 256 + nt];
        sq  += part[((b * 16 + g) * 2 + 1) * 256 + nt];
    }
    #pragma unroll
    for (int off = 32; off > 0; off >>= 1) {
        sum += __shfl_down(sum, off);
        sq  += __shfl_down(sq, off);
    }
    if (lane == 0) {
        float cnt = 16.f * (float)NK_;
        float mean = sum / cnt;
        float var = fmaxf(sq / cnt - mean * mean, 0.f);
        float sc = gamma[c] * rsqrtf(var + EPS_);
        ga[wv] = sc;
        sh[wv] = beta[c] - mean * sc;
    }
}

// ---------------- final: out = relu(a*max_k + s)  (valid since a>0) ----------------
__global__ __launch_bounds__(256) void apply_kernel(const float* __restrict__ m4,
    const float* __restrict__ ga, const float* __restrict__ sh, float* __restrict__ out)
{
    int t = blockIdx.x * 256 + threadIdx.x;   // b*256*N + c*N + n
    int bc = t >> 12;
    out[t] = fmaxf(fmaf(m4[t], ga[bc], sh[bc]), 0.f);
}

extern "C" void kernel_launch(void* const* d_in, const int* in_sizes, int n_in,
                              void* d_out, int out_size, void* d_ws, size_t ws_size,
                              hipStream_t stream)
{
    const float* pts = (const float*)d_in[0];
    const float* W1 = (const float*)d_in[1];
    const float* g1 = (const float*)d_in[2];
    const float* bt1 = (const float*)d_in[3];
    const float* W2 = (const float*)d_in[4];
    const float* g2 = (const float*)d_in[5];
    const float* bt2 = (const float*)d_in[6];
    const float* W3 = (const float*)d_in[7];
    const float* g3 = (const float*)d_in[8];
    const float* bt3 = (const float*)d_in[9];
    const float* W4 = (const float*)d_in[10];
    const float* g4 = (const float*)d_in[11];
    const float* bt4 = (const float*)d_in[12];
    float* out = (float*)d_out;

    char* ws = (char*)d_ws;
    size_t off = 0;
    auto alloc = [&](size_t bytes) -> void* {
        void* p = ws + off;
        off = (off + bytes + 255) & ~(size_t)255;
        return p;
    };
    int*   idx  = (int*)  alloc((size_t)B_ * NK_ * 4);           // 1.3 MB
    float* x0   = (float*)alloc((size_t)B_ * 13 * NK_ * 4);      // 17 MB
    unsigned short* y2g = (unsigned short*)alloc((size_t)B_ * 8 * NK_ * 8 * 2);   // 42 MB
    unsigned short* y3g = (unsigned short*)alloc((size_t)B_ * 16 * NK_ * 8 * 2);  // 84 MB
    unsigned short* y1g = y3g;   // ALIAS: y1g (42 MB) lives in y3g's buffer; dead before stage3 writes
    float* m4   = (float*)alloc((size_t)B_ * 256 * N_ * 4);      // 16.8 MB
    bf16*  w2b  = (bf16*) alloc(64 * 64 * 2);                    // 8 KB
    bf16*  w3b  = (bf16*) alloc(128 * 64 * 2);                   // 16 KB
    bf16*  w4b  = (bf16*) alloc(256 * 128 * 2);                  // 64 KB
    float* p1   = (float*)alloc((size_t)B_ * NBLK_ * 32 * 4);    // 164 KB
    float* p2m  = (float*)alloc((size_t)B_ * 1024 * 32 * 4);     // 0.5 MB
    float* p3m  = (float*)alloc((size_t)B_ * 1024 * 32 * 4);     // 0.5 MB
    float* part4= (float*)alloc(4 * 16 * 2 * 256 * 4);           // 128 KB
    float* a1 = (float*)alloc(B_ * 64 * 4);
    float* s1 = (float*)alloc(B_ * 64 * 4);
    float* a2 = (float*)alloc(B_ * 64 * 4);
    float* s2 = (float*)alloc(B_ * 64 * 4);
    float* a3 = (float*)alloc(B_ * 128 * 4);
    float* s3 = (float*)alloc(B_ * 128 * 4);
    float* a4 = (float*)alloc(B_ * 256 * 4);
    float* s4 = (float*)alloc(B_ * 256 * 4);
    (void)ws_size; (void)in_sizes; (void)n_in; (void)out_size;

    knn_kernel<<<(B_ * N_) / 4, 256, 0, stream>>>(pts, idx);
    wcast_kernel<<<16, 256, 0, stream>>>(W2, w2b, 64 * 64);
    wcast_kernel<<<32, 256, 0, stream>>>(W3, w3b, 128 * 64);
    wcast_kernel<<<128, 256, 0, stream>>>(W4, w4b, 256 * 128);
    feature_kernel<<<(B_ * NK_) / 256, 256, 0, stream>>>(pts, idx, x0);

    stage1_kernel<<<dim3(NBLK_, B_), 256, 0, stream>>>(x0, W1, y1g, p1);
    finalize_kernel<64><<<64, 256, 0, stream>>>(p1, g1, bt1, a1, s1);

    prep64_kernel<<<(int)(((size_t)B_ * 8 * NK_) / 256), 256, 0, stream>>>(y1g, a1, s1);
    stage2_mfma_kernel<<<dim3(N_ / 16, 1, B_), 256, 0, stream>>>((const short*)y1g, (const short*)w2b, y2g, p2m);
    finalizeM_kernel<64><<<64, 256, 0, stream>>>(p2m, g2, bt2, a2, s2);

    prep64_kernel<<<(int)(((size_t)B_ * 8 * NK_) / 256), 256, 0, stream>>>(y2g, a2, s2);
    stage3_mfma_kernel<<<dim3(N_ / 16, 1, B_), 256, 0, stream>>>((const short*)y2g, (const short*)w3b, y3g, p3m);
    finalizeM_kernel<128><<<128, 256, 0, stream>>>(p3m, g3, bt3, a3, s3);

    prep4_kernel<<<(int)(((size_t)B_ * 16 * NK_) / 256), 256, 0, stream>>>(y3g, a3, s3);
    conv4_mfma_kernel<<<dim3(N_ / 16, 1, B_), 256, 0, stream>>>((const short*)y3g, (const short*)w4b, m4, part4);
    finalize4_kernel<<<256, 256, 0, stream>>>(part4, g4, bt4, a4, s4);

    apply_kernel<<<(B_ * 256 * N_) / 256, 256, 0, stream>>>(m4, a4, s4, out);
}